// Round 3
// baseline (381.974 us; speedup 1.0000x reference)
//
#include <hip/hip_runtime.h>
#include <math.h>

#define TPB 256
#define CTPB 512
#define KTPB 512

// ---------- complex helpers ----------
__device__ __forceinline__ float2 cmul(float2 a, float2 b) {
    return make_float2(a.x * b.x - a.y * b.y, a.x * b.y + a.y * b.x);
}
__device__ __forceinline__ float2 cdivf(float2 a, float2 b) {
    float inv = 1.0f / (b.x * b.x + b.y * b.y);
    return make_float2((a.x * b.x + a.y * b.y) * inv, (a.y * b.x - a.x * b.y) * inv);
}
__device__ __forceinline__ float2 cadd(float2 a, float2 b) { return make_float2(a.x + b.x, a.y + b.y); }
__device__ __forceinline__ float2 csub(float2 a, float2 b) { return make_float2(a.x - b.x, a.y - b.y); }
__device__ __forceinline__ float2 mul_i(float2 a, float d) {  // a * (i*d)
    return make_float2(-d * a.y, d * a.x);
}
__device__ __forceinline__ int brev11(int x) { return (int)(__brev((unsigned)x) >> 21); }
// base-8 digit reversal of a 12-bit index (4 digits)
__device__ __forceinline__ int rev8(int x) {
    return ((x & 7) << 9) | (((x >> 3) & 7) << 6) | (((x >> 6) & 7) << 3) | ((x >> 9) & 7);
}
// LDS bank swizzle. GF(2)-LINEAR: swz(a^b) == swz(a)^swz(b) -> per-tap offsets fold
// to compile-time XOR constants.
__device__ __forceinline__ int swz(int i) { return i ^ ((i >> 4) & 15) ^ ((i >> 8) & 15); }

// ---------- 8-point DFT cores ----------
__device__ __forceinline__ void dft8(const float2* x, float2* y, float d) {
    const float r = 0.70710678118f;
    float2 s0 = cadd(x[0], x[4]), t0 = csub(x[0], x[4]);
    float2 s1 = cadd(x[1], x[5]), t1 = csub(x[1], x[5]);
    float2 s2 = cadd(x[2], x[6]), t2 = csub(x[2], x[6]);
    float2 s3 = cadd(x[3], x[7]), t3 = csub(x[3], x[7]);
    t1 = cmul(t1, make_float2(r, d * r));
    t2 = mul_i(t2, d);
    t3 = cmul(t3, make_float2(-r, d * r));
    float2 u0 = cadd(s0, s2), v0 = csub(s0, s2);
    float2 u1 = cadd(s1, s3), v1 = mul_i(csub(s1, s3), d);
    y[0] = cadd(u0, u1); y[4] = csub(u0, u1);
    y[2] = cadd(v0, v1); y[6] = csub(v0, v1);
    float2 p0 = cadd(t0, t2), q0 = csub(t0, t2);
    float2 p1 = cadd(t1, t3), q1 = mul_i(csub(t1, t3), d);
    y[1] = cadd(p0, p1); y[5] = csub(p0, p1);
    y[3] = cadd(q0, q1); y[7] = csub(q0, q1);
}

// dft8 with x[4..7] == 0 (zero-padded upper half): level 1 vanishes (s_i = t_i = x_i)
__device__ __forceinline__ void dft8z(float2 x0, float2 x1, float2 x2, float2 x3,
                                      float2* y, float d) {
    const float r = 0.70710678118f;
    float2 u0 = cadd(x0, x2), v0 = csub(x0, x2);
    float2 u1 = cadd(x1, x3), v1 = mul_i(csub(x1, x3), d);
    float2 t1 = cmul(x1, make_float2(r, d * r));
    float2 t2 = mul_i(x2, d);
    float2 t3 = cmul(x3, make_float2(-r, d * r));
    float2 p0 = cadd(x0, t2), q0 = csub(x0, t2);
    float2 p1 = cadd(t1, t3), q1 = mul_i(csub(t1, t3), d);
    y[0] = cadd(u0, u1); y[4] = csub(u0, u1);
    y[2] = cadd(v0, v1); y[6] = csub(v0, v1);
    y[1] = cadd(p0, p1); y[5] = csub(p0, p1);
    y[3] = cadd(q0, q1); y[7] = csub(q0, q1);
}

// dft8 computing only outputs y[0..3] (the '+' halves) — for the discarded tail
__device__ __forceinline__ void dft8_lo(const float2* x, float2* y, float d) {
    const float r = 0.70710678118f;
    float2 s0 = cadd(x[0], x[4]), t0 = csub(x[0], x[4]);
    float2 s1 = cadd(x[1], x[5]), t1 = csub(x[1], x[5]);
    float2 s2 = cadd(x[2], x[6]), t2 = csub(x[2], x[6]);
    float2 s3 = cadd(x[3], x[7]), t3 = csub(x[3], x[7]);
    t1 = cmul(t1, make_float2(r, d * r));
    t2 = mul_i(t2, d);
    t3 = cmul(t3, make_float2(-r, d * r));
    float2 u0 = cadd(s0, s2), v0 = csub(s0, s2);
    float2 u1 = cadd(s1, s3), v1 = mul_i(csub(s1, s3), d);
    y[0] = cadd(u0, u1);
    y[2] = cadd(v0, v1);
    float2 p0 = cadd(t0, t2), q0 = csub(t0, t2);
    float2 p1 = cadd(t1, t3), q1 = mul_i(csub(t1, t3), d);
    y[1] = cadd(p0, p1);
    y[3] = cadd(q0, q1);
}

// ---------- single radix-8 stages for conv (1 butterfly/thread, N=4096, NT=512) ----------
template <int HB, int DIR>
__device__ __forceinline__ void dif_stage(float2* s, int tid) {
    __syncthreads();
    const int h = 1 << HB;
    int j = tid & (h - 1);
    int base = ((tid >> HB) << (HB + 3)) + j;
    int s0 = swz(base);
    float2 x[8];
#pragma unroll
    for (int k = 0; k < 8; ++k) x[k] = s[s0 ^ swz(k << HB)];
    float2 y[8];
    dft8(x, y, (float)DIR);
    if constexpr (HB != 0) {
        float ang = (float)DIR * 6.283185307179586f / (float)(h << 3) * (float)j;
        float c, sn;
        __sincosf(ang, &sn, &c);
        float2 w = make_float2(c, sn), wm = w;
        s[s0] = y[0];
#pragma unroll
        for (int m = 1; m < 8; ++m) {
            s[s0 ^ swz(m << HB)] = cmul(wm, y[m]);
            wm = cmul(wm, w);
        }
    } else {  // j == 0 -> w == 1: no twiddles
#pragma unroll
        for (int m = 0; m < 8; ++m) s[s0 ^ swz(m << HB)] = y[m];
    }
}

template <int HB, int DIR>
__device__ __forceinline__ void dit_stage(float2* s, int tid) {
    __syncthreads();
    const int h = 1 << HB;
    int j = tid & (h - 1);
    int base = ((tid >> HB) << (HB + 3)) + j;
    int s0 = swz(base);
    float2 x[8];
    if constexpr (HB != 0) {
        float ang = (float)DIR * 6.283185307179586f / (float)(h << 3) * (float)j;
        float c, sn;
        __sincosf(ang, &sn, &c);
        float2 w = make_float2(c, sn);
        x[0] = s[s0];
        float2 wm = w;
#pragma unroll
        for (int k = 1; k < 8; ++k) {
            x[k] = cmul(wm, s[s0 ^ swz(k << HB)]);
            wm = cmul(wm, w);
        }
    } else {  // j == 0 -> no twiddles
#pragma unroll
        for (int k = 0; k < 8; ++k) x[k] = s[s0 ^ swz(k << HB)];
    }
    float2 y[8];
    dft8(x, y, (float)DIR);
#pragma unroll
    for (int m = 0; m < 8; ++m) s[s0 ^ swz(m << HB)] = y[m];
}

// ---------- generic radix-8 DIF (for kprep), with h=1 twiddle skip ----------
template <int LOGN, int NT>
__device__ void fft8_dif(float2* s, int tid, float dir) {
    const int N = 1 << LOGN;
#pragma unroll
    for (int hb = LOGN - 3; hb >= 0; hb -= 3) {
        const int h = 1 << hb;
        const float astep = dir * 6.283185307179586f / (float)(h << 3);
        __syncthreads();
#pragma unroll
        for (int it = 0; it < (N >> 3) / NT; ++it) {
            const int b = tid + it * NT;
            int j = b & (h - 1);
            int base = ((b >> hb) << (hb + 3)) + j;
            int s0 = swz(base);
            float2 x[8];
#pragma unroll
            for (int k = 0; k < 8; ++k) x[k] = s[s0 ^ swz(k << hb)];
            float2 y[8];
            dft8(x, y, dir);
            if (hb != 0) {  // folds: hb is unroll-constant
                float ang = astep * (float)j;
                float c, sn;
                __sincosf(ang, &sn, &c);
                float2 w = make_float2(c, sn), wm = w;
                s[s0] = y[0];
#pragma unroll
                for (int m = 1; m < 8; ++m) {
                    s[s0 ^ swz(m << hb)] = cmul(wm, y[m]);
                    wm = cmul(wm, w);
                }
            } else {
#pragma unroll
                for (int m = 0; m < 8; ++m) s[s0 ^ swz(m << hb)] = y[m];
            }
        }
    }
    __syncthreads();
}

// ---------- radix-2 DIF (unswizzled), for the 2048-pt kernel inverse only ----------
template <int LOGN, int NT>
__device__ void fft_dif2(float2* s, int tid, float dir) {
    const int N = 1 << LOGN;
    for (int st = LOGN - 1; st >= 0; --st) {
        __syncthreads();
        int half = 1 << st;
        for (int b = tid; b < (N >> 1); b += NT) {
            int j  = b & (half - 1);
            int i0 = ((b >> st) << (st + 1)) + j;
            int i1 = i0 + half;
            float2 u = s[i0], v = s[i1];
            float2 d = make_float2(u.x - v.x, u.y - v.y);
            s[i0] = make_float2(u.x + v.x, u.y + v.y);
            if (half > 1) {
                float ang = dir * 3.14159265358979f * (float)j / (float)half;
                float c, sn;
                __sincosf(ang, &sn, &c);
                s[i1] = cmul(make_float2(c, sn), d);
            } else {
                s[i1] = d;
            }
        }
    }
    __syncthreads();
}

// ---------- kernel A: k_f[h, f] via Cauchy + Woodbury, collapsed pair algebra ----------
__global__ __launch_bounds__(TPB) void kf_kernel(
    const float* __restrict__ log_dt, const float* __restrict__ w_ri,
    const float* __restrict__ Bri, const float* __restrict__ Cri,
    float2* __restrict__ kf) {
    __shared__ float2 wds[32];
    __shared__ float aab[4][32], rab[4][32];
    __shared__ float qn[32], pn[32];
    const int h   = blockIdx.x;
    const int tid = threadIdx.x;
    const float dt = expf(log_dt[h]);
    if (tid < 32) {
        float wr = w_ri[2 * tid] * dt, wi = w_ri[2 * tid + 1] * dt;
        wds[tid] = make_float2(wr, wi);
        qn[tid]  = wr * wr + wi * wi;
        pn[tid]  = -2.0f * wr;
    }
    __syncthreads();
    if (tid < 128) {
        int a = tid >> 6, b = (tid >> 5) & 1, n = tid & 31;
        const float* Cp = Cri + (((h * 2 + a) * 32) + n) * 2;
        const float* Bp = Bri + (((h * 2 + b) * 32) + n) * 2;
        float Cr = Cp[0], Ci = Cp[1], Br = Bp[0], Bi = Bp[1];
        float2 v = make_float2(Cr * Br + Ci * Bi, Cr * Bi - Ci * Br);  // conj(C)*B
        float2 wd = wds[n];
        aab[a * 2 + b][n] = -2.0f * (v.x * wd.x + v.y * wd.y);
        rab[a * 2 + b][n] = 2.0f * v.x;
    }
    __syncthreads();
    const int by   = blockIdx.y;
    const int fend = (by == 3) ? 2049 : (by + 1) * 512;
    for (int f = by * 512 + tid; f < fend; f += TPB) {
        float th = (6.283185307179586f / 4096.0f) * (float)f;
        float cf = cosf(th), sf = sinf(th);
        float2 den = make_float2(1.0f + cf, -sf);      // 1 + freq
        float zt  = 2.0f * tanf(0.5f * th);
        float zt2 = zt * zt;
        float2 r00 = make_float2(0.f, 0.f), r01 = r00, r10 = r00, r11 = r00;
        for (int n = 0; n < 32; ++n) {
            float c   = qn[n] - zt2;
            float d   = pn[n] * zt;
            float inv = 1.0f / (c * c + d * d);
            float cc = c * inv, dd = d * inv;
            float a0 = aab[0][n], b0 = rab[0][n] * zt;
            r00.x += a0 * cc + b0 * dd; r00.y += b0 * cc - a0 * dd;
            float a1 = aab[1][n], b1 = rab[1][n] * zt;
            r01.x += a1 * cc + b1 * dd; r01.y += b1 * cc - a1 * dd;
            float a2 = aab[2][n], b2 = rab[2][n] * zt;
            r10.x += a2 * cc + b2 * dd; r10.y += b2 * cc - a2 * dd;
            float a3 = aab[3][n], b3 = rab[3][n] * zt;
            r11.x += a3 * cc + b3 * dd; r11.y += b3 * cc - a3 * dd;
        }
        r00.x *= dt; r00.y *= dt; r01.x *= dt; r01.y *= dt;
        r10.x *= dt; r10.y *= dt; r11.x *= dt; r11.y *= dt;
        float2 q  = cdivf(cmul(r01, r10), make_float2(1.0f + r11.x, r11.y));
        float2 k0 = make_float2(r00.x - q.x, r00.y - q.y);
        float2 kv = cmul(k0, cdivf(make_float2(2.0f, 0.0f), den));
        kf[h * 2049 + f] = kv;
    }
}

// ---------- kernel B (fused): irfft_4096(k_f) -> zero-pad -> rfft_8192, store digit-rev
// with 1/4096 inverse-FFT scale pre-folded; row stride 4098 (16B-aligned rows) ----------
__global__ __launch_bounds__(KTPB) void kprep_kernel(const float2* __restrict__ kf,
                                                     float2* __restrict__ Kt) {
    __shared__ float2 s[4096];
    const int hh = blockIdx.x, tid = threadIdx.x;
    const float2* X = kf + hh * 2049;
    for (int m = tid; m < 2048; m += KTPB) {
        float2 Xm = X[m];
        float2 Xc = X[2048 - m];
        if (m == 0) { Xm.y = 0.0f; Xc.y = 0.0f; }
        float2 A  = make_float2(Xm.x + Xc.x, Xm.y - Xc.y);
        float2 Bv = make_float2(Xm.x - Xc.x, Xm.y + Xc.y);
        float ang = (3.14159265358979f / 2048.0f) * (float)m;
        float c, sn;
        __sincosf(ang, &sn, &c);
        float2 O = cmul(make_float2(c, sn), Bv);
        s[m] = make_float2(0.5f * (A.x - O.y), 0.5f * (A.y + O.x));
    }
    fft_dif2<11, KTPB>(s, tid, +1.0f);  // inverse, natural-in -> bitrev-out (unswizzled)
    float2 reg[4];
    const float sc = 1.0f / 2048.0f;
#pragma unroll
    for (int i = 0; i < 4; ++i) {
        int t = tid + KTPB * i;  // 0..2047
        float2 v = s[brev11(t)];
        reg[i] = make_float2(v.x * sc, v.y * sc);
    }
    __syncthreads();
#pragma unroll
    for (int i = 0; i < 4; ++i) {
        int t = tid + KTPB * i;
        s[swz(t)]        = reg[i];
        s[swz(t + 2048)] = make_float2(0.f, 0.f);
    }
    fft8_dif<12, KTPB>(s, tid, -1.0f);  // slot p holds Y[rev8(p)]
    float2* K = Kt + (size_t)hh * 4098;
    const float hsc = 0.5f / 4096.0f;   // unpack 1/2 * ifft 1/4096
    for (int p = tid; p < 4096; p += KTPB) {
        int j  = rev8(p);
        int jc = (4096 - j) & 4095;
        int pc = rev8(jc);
        float2 Yj = s[swz(p)], Yc = s[swz(pc)];
        float2 A  = make_float2(Yj.x + Yc.x, Yj.y - Yc.y);
        float2 Bv = make_float2(Yj.x - Yc.x, Yj.y + Yc.y);
        float ang = -(3.14159265358979f / 4096.0f) * (float)j;
        float c, sn;
        __sincosf(ang, &sn, &c);
        float2 t2 = cmul(make_float2(c, sn), make_float2(Bv.y, -Bv.x));
        K[p] = make_float2(hsc * (A.x + t2.x), hsc * (A.y + t2.y));
        if (p == 0) K[4096] = make_float2((2.0f * hsc) * (Yj.x - Yj.y), 0.0f);
    }
}

// ---------- transpose in: x[b,t,h] -> xt[(b*512+h), t], float4 both sides ----------
__global__ __launch_bounds__(TPB) void transpose_in(const float* __restrict__ x,
                                                    float* __restrict__ xt) {
    __shared__ float tile[64][65];
    const int b = blockIdx.z, t0 = blockIdx.y * 64, h0 = blockIdx.x * 64;
    const int tid = threadIdx.x;
    const float4* xv = (const float4*)(x + ((size_t)b * 4096 + t0) * 512 + h0);
#pragma unroll
    for (int i = 0; i < 4; ++i) {
        int idx = tid + TPB * i;       // 0..1023
        int tl = idx >> 4, hq = idx & 15;
        float4 v = xv[(size_t)tl * 128 + hq];
        tile[tl][hq * 4 + 0] = v.x; tile[tl][hq * 4 + 1] = v.y;
        tile[tl][hq * 4 + 2] = v.z; tile[tl][hq * 4 + 3] = v.w;
    }
    __syncthreads();
    float* xo = xt + ((size_t)(b * 512 + h0)) * 4096 + t0;
#pragma unroll
    for (int i = 0; i < 4; ++i) {
        int idx = tid + TPB * i;
        int hl = idx >> 4, tq = idx & 15;
        float4 v = make_float4(tile[tq * 4 + 0][hl], tile[tq * 4 + 1][hl],
                               tile[tq * 4 + 2][hl], tile[tq * 4 + 3][hl]);
        ((float4*)(xo + (size_t)hl * 4096))[tq] = v;
    }
}

// ---------- fused conv: y = irfft8192(rfft8192(x)*K~)[0:4096] + D*x, radix-8,
// reg end-stages; Hermitian pointwise as on-the-fly P/Q linear map fused with h=1 stages:
//   Z'_p = P*Z_p + Q*conj(Z_pc),  pc_k = RM|(7-k) contiguous per thread
//   P = ½(1-sinθ)K_j + ½(1+sinθ)conj(K_c),  Q = (i·cosθ/2)(K_j - conj(K_c))
//   θ_k = πk/8 + πJb/4096 -> one sincos/thread + compile-time angle addition.
//   K loads issued IN-LOOP after the barrier (nothing K-related live across barriers);
//   __launch_bounds__ min-waves=8 caps VGPR at 64 (r2 lesson: 80 VGPR halves occupancy) ----------
__global__ __launch_bounds__(CTPB, 8) void conv_kernel(const float* xt,
                                                       const float2* __restrict__ Kt,
                                                       const float* __restrict__ Dv,
                                                       float* yt) {
    __shared__ float2 s[4096];
    const int row = blockIdx.x, tid = threadIdx.x;
    const int hch = row & 511;
    const int stid = swz(tid);
    const float2* xr = (const float2*)(xt + (size_t)row * 4096);

    // ---- D1 (DIF h=512) in registers; upper half is the zero pad -> dft8z
    {
        float2 x0 = xr[tid], x1 = xr[tid + 512], x2 = xr[tid + 1024], x3 = xr[tid + 1536];
        float2 y[8];
        dft8z(x0, x1, x2, x3, y, -1.0f);
        float ang = -(6.283185307179586f / 4096.0f) * (float)tid;
        float c, sn;
        __sincosf(ang, &sn, &c);
        float2 w = make_float2(c, sn), wm = w;
        s[stid] = y[0];
#pragma unroll
        for (int m = 1; m < 8; ++m) {
            s[stid ^ swz(m << 9)] = cmul(wm, y[m]);
            wm = cmul(wm, w);
        }
    }
    dif_stage<6, -1>(s, tid);
    dif_stage<3, -1>(s, tid);
    // ---- fused: dif h=1 (regs) + on-the-fly P/Q pointwise + dit h=1 (regs)
    {
        __syncthreads();
        const int p0  = tid << 3;       // 8 contiguous slots per thread
        const int sp0 = swz(p0);
        float2 x[8], y[8];
#pragma unroll
        for (int k = 0; k < 8; ++k) x[k] = s[sp0 ^ k];
        dft8(x, y, -1.0f);
#pragma unroll
        for (int k = 0; k < 8; ++k) s[sp0 ^ k] = y[k];  // publish for partner reads
        // j_k = (k<<9)|Jb ; partner slot pc_k = RM|(7-k) (contiguous descending)
        const int Jb = rev8(p0);
        const int RM = rev8(512 - Jb);                   // valid when Jb!=0
        const float2* Krow = Kt + (size_t)hch * 4098;
        float sphi, cphi;
        __sincosf((3.14159265358979f / 4096.0f) * (float)Jb, &sphi, &cphi);
        __syncthreads();
        // sin/cos(pi*k/8) — fold at compile time in the unrolled loop
        const float SK[8] = {0.0f, 0.3826834324f, 0.7071067812f, 0.9238795325f,
                             1.0f, 0.9238795325f, 0.7071067812f, 0.3826834324f};
        const float CK[8] = {1.0f, 0.9238795325f, 0.7071067812f, 0.3826834324f,
                             0.0f, -0.3826834324f, -0.7071067812f, -0.9238795325f};
        const float4* o4p = (const float4*)(Krow + p0);  // own K, rolling float4
        float4 o4 = make_float4(0.f, 0.f, 0.f, 0.f);
#pragma unroll
        for (int k = 0; k < 8; ++k) {
            if ((k & 1) == 0) o4 = o4p[k >> 1];          // in-loop: short live range
            int pck = Jb ? (RM | (7 - k)) : ((8 - k) & 7);
            float2 Kc = Krow[(Jb | k) ? pck : 4096];     // in-loop partner K
            float2 zc = s[swz(pck)];
            float2 zk = y[k];
            float sth = SK[k] * cphi + CK[k] * sphi;     // sin(θ_k)
            float cth = CK[k] * cphi - SK[k] * sphi;     // cos(θ_k)
            float2 Kj = (k & 1) ? make_float2(o4.z, o4.w) : make_float2(o4.x, o4.y);
            float ap = 0.5f * (1.0f - sth), bp = 0.5f * (1.0f + sth);
            float Px = ap * Kj.x + bp * Kc.x;
            float Py = ap * Kj.y - bp * Kc.y;
            float hc = 0.5f * cth;
            float Qx = -hc * (Kj.y + Kc.y);
            float Qy =  hc * (Kj.x - Kc.x);
            y[k] = make_float2(Px * zk.x - Py * zk.y + Qx * zc.x + Qy * zc.y,
                               Px * zk.y + Py * zk.x + Qy * zc.x - Qx * zc.y);
        }
        __syncthreads();                                 // all partner reads done before overwrite
        dft8(y, x, 1.0f);
#pragma unroll
        for (int k = 0; k < 8; ++k) s[sp0 ^ k] = x[k];
    }
    dit_stage<3, 1>(s, tid);
    dit_stage<6, 1>(s, tid);
    __syncthreads();
    // ---- I4 (DIT h=512) in registers; keep only first 4096 samples; fuse D*x skip
    // (1/4096 inverse scale pre-folded into Kt by kprep)
    {
        float ang = (6.283185307179586f / 4096.0f) * (float)tid;
        float c, sn;
        __sincosf(ang, &sn, &c);
        float2 w = make_float2(c, sn);
        float2 x[8];
        x[0] = s[stid];
        float2 wm = w;
#pragma unroll
        for (int k = 1; k < 8; ++k) {
            x[k] = cmul(wm, s[stid ^ swz(k << 9)]);
            wm = cmul(wm, w);
        }
        float2 y[4];
        dft8_lo(x, y, 1.0f);
        const float D = Dv[hch];
        float2* yo = (float2*)(yt + (size_t)row * 4096);
#pragma unroll
        for (int m = 0; m < 4; ++m) {
            int t2 = tid + (m << 9);
            float2 xin = xr[t2];  // re-read own row (L2-warm); xt/yt alias is per-element safe
            yo[t2] = make_float2(y[m].x + D * xin.x, y[m].y + D * xin.y);
        }
    }
}

// ---------- transpose out (pure): out[b,t,h] = yt[(b*512+h),t] ----------
__global__ __launch_bounds__(TPB) void transpose_out(const float* __restrict__ yt,
                                                     float* __restrict__ out) {
    __shared__ float tile[64][65];
    const int b = blockIdx.z, t0 = blockIdx.y * 64, h0 = blockIdx.x * 64;
    const int tid = threadIdx.x;
    const float* yp = yt + ((size_t)(b * 512 + h0)) * 4096 + t0;
#pragma unroll
    for (int i = 0; i < 4; ++i) {
        int idx = tid + TPB * i;
        int hl = idx >> 4, tq = idx & 15;
        float4 v = ((const float4*)(yp + (size_t)hl * 4096))[tq];
        tile[tq * 4 + 0][hl] = v.x; tile[tq * 4 + 1][hl] = v.y;
        tile[tq * 4 + 2][hl] = v.z; tile[tq * 4 + 3][hl] = v.w;
    }
    __syncthreads();
    float4* ov = (float4*)(out + ((size_t)b * 4096 + t0) * 512 + h0);
#pragma unroll
    for (int i = 0; i < 4; ++i) {
        int idx = tid + TPB * i;
        int tl = idx >> 4, hq = idx & 15;
        float4 v = make_float4(tile[tl][4 * hq + 0], tile[tl][4 * hq + 1],
                               tile[tl][4 * hq + 2], tile[tl][4 * hq + 3]);
        ov[(size_t)tl * 128 + hq] = v;
    }
}

extern "C" void kernel_launch(void* const* d_in, const int* in_sizes, int n_in,
                              void* d_out, int out_size, void* d_ws, size_t ws_size,
                              hipStream_t stream) {
    (void)in_sizes; (void)n_in; (void)out_size; (void)ws_size;
    const float* x      = (const float*)d_in[0];  // [8,4096,512]
    const float* log_dt = (const float*)d_in[1];  // [512]
    const float* w_ri   = (const float*)d_in[2];  // [32,2]
    const float* Bri    = (const float*)d_in[3];  // [512,2,32,2]
    const float* Cri    = (const float*)d_in[4];  // [512,2,32,2]
    const float* Dv     = (const float*)d_in[5];  // [512]
    float* out = (float*)d_out;

    char* ws = (char*)d_ws;
    // Layout (stream order makes the alias safe):
    //   kf aliases xt[0:8.4MB) — written by kf_kernel, fully consumed by kprep_kernel
    //   BEFORE transpose_in overwrites xt.  xt reused as yt by conv (in-place).
    float*  xt = (float*)(ws);                  // 8*512*4096*4 = 67,108,864 B
    float2* kf = (float2*)(ws);                 // 512*2049*8   =  8,392,704 B (aliased)
    float2* Kt = (float2*)(ws + 67108864);      // 512*4098*8   = 16,785,408 B (end ~83.9 MB)

    kf_kernel<<<dim3(512, 4), TPB, 0, stream>>>(log_dt, w_ri, Bri, Cri, kf);
    kprep_kernel<<<512, KTPB, 0, stream>>>(kf, Kt);
    transpose_in<<<dim3(8, 64, 8), TPB, 0, stream>>>(x, xt);
    conv_kernel<<<4096, CTPB, 0, stream>>>(xt, Kt, Dv, xt);  // y(+skip) overwrites xt rows
    transpose_out<<<dim3(8, 64, 8), TPB, 0, stream>>>(xt, out);
}

// Round 5
// 294.168 us; speedup vs baseline: 1.2985x; 1.2985x over previous
//
#include <hip/hip_runtime.h>
#include <math.h>

#define TPB 256
#define CTPB 512
#define KTPB 512

// ---------- complex helpers ----------
__device__ __forceinline__ float2 cmul(float2 a, float2 b) {
    return make_float2(a.x * b.x - a.y * b.y, a.x * b.y + a.y * b.x);
}
__device__ __forceinline__ float2 cdivf(float2 a, float2 b) {
    float inv = 1.0f / (b.x * b.x + b.y * b.y);
    return make_float2((a.x * b.x + a.y * b.y) * inv, (a.y * b.x - a.x * b.y) * inv);
}
__device__ __forceinline__ float2 cadd(float2 a, float2 b) { return make_float2(a.x + b.x, a.y + b.y); }
__device__ __forceinline__ float2 csub(float2 a, float2 b) { return make_float2(a.x - b.x, a.y - b.y); }
__device__ __forceinline__ float2 mul_i(float2 a, float d) {  // a * (i*d)
    return make_float2(-d * a.y, d * a.x);
}
__device__ __forceinline__ int brev11(int x) { return (int)(__brev((unsigned)x) >> 21); }
// base-8 digit reversal of a 12-bit index (4 digits)
__device__ __forceinline__ int rev8(int x) {
    return ((x & 7) << 9) | (((x >> 3) & 7) << 6) | (((x >> 6) & 7) << 3) | ((x >> 9) & 7);
}
// LDS bank swizzle. GF(2)-LINEAR: swz(a^b) == swz(a)^swz(b) -> per-tap offsets fold
// to compile-time XOR constants.
__device__ __forceinline__ int swz(int i) { return i ^ ((i >> 4) & 15) ^ ((i >> 8) & 15); }

// ---------- 8-point DFT cores ----------
__device__ __forceinline__ void dft8(const float2* x, float2* y, float d) {
    const float r = 0.70710678118f;
    float2 s0 = cadd(x[0], x[4]), t0 = csub(x[0], x[4]);
    float2 s1 = cadd(x[1], x[5]), t1 = csub(x[1], x[5]);
    float2 s2 = cadd(x[2], x[6]), t2 = csub(x[2], x[6]);
    float2 s3 = cadd(x[3], x[7]), t3 = csub(x[3], x[7]);
    t1 = cmul(t1, make_float2(r, d * r));
    t2 = mul_i(t2, d);
    t3 = cmul(t3, make_float2(-r, d * r));
    float2 u0 = cadd(s0, s2), v0 = csub(s0, s2);
    float2 u1 = cadd(s1, s3), v1 = mul_i(csub(s1, s3), d);
    y[0] = cadd(u0, u1); y[4] = csub(u0, u1);
    y[2] = cadd(v0, v1); y[6] = csub(v0, v1);
    float2 p0 = cadd(t0, t2), q0 = csub(t0, t2);
    float2 p1 = cadd(t1, t3), q1 = mul_i(csub(t1, t3), d);
    y[1] = cadd(p0, p1); y[5] = csub(p0, p1);
    y[3] = cadd(q0, q1); y[7] = csub(q0, q1);
}

// dft8 with x[4..7] == 0 (zero-padded upper half): level 1 vanishes (s_i = t_i = x_i)
__device__ __forceinline__ void dft8z(float2 x0, float2 x1, float2 x2, float2 x3,
                                      float2* y, float d) {
    const float r = 0.70710678118f;
    float2 u0 = cadd(x0, x2), v0 = csub(x0, x2);
    float2 u1 = cadd(x1, x3), v1 = mul_i(csub(x1, x3), d);
    float2 t1 = cmul(x1, make_float2(r, d * r));
    float2 t2 = mul_i(x2, d);
    float2 t3 = cmul(x3, make_float2(-r, d * r));
    float2 p0 = cadd(x0, t2), q0 = csub(x0, t2);
    float2 p1 = cadd(t1, t3), q1 = mul_i(csub(t1, t3), d);
    y[0] = cadd(u0, u1); y[4] = csub(u0, u1);
    y[2] = cadd(v0, v1); y[6] = csub(v0, v1);
    y[1] = cadd(p0, p1); y[5] = csub(p0, p1);
    y[3] = cadd(q0, q1); y[7] = csub(q0, q1);
}

// dft8 computing only outputs y[0..3] (the '+' halves) — for the discarded tail
__device__ __forceinline__ void dft8_lo(const float2* x, float2* y, float d) {
    const float r = 0.70710678118f;
    float2 s0 = cadd(x[0], x[4]), t0 = csub(x[0], x[4]);
    float2 s1 = cadd(x[1], x[5]), t1 = csub(x[1], x[5]);
    float2 s2 = cadd(x[2], x[6]), t2 = csub(x[2], x[6]);
    float2 s3 = cadd(x[3], x[7]), t3 = csub(x[3], x[7]);
    t1 = cmul(t1, make_float2(r, d * r));
    t2 = mul_i(t2, d);
    t3 = cmul(t3, make_float2(-r, d * r));
    float2 u0 = cadd(s0, s2), v0 = csub(s0, s2);
    float2 u1 = cadd(s1, s3), v1 = mul_i(csub(s1, s3), d);
    y[0] = cadd(u0, u1);
    y[2] = cadd(v0, v1);
    float2 p0 = cadd(t0, t2), q0 = csub(t0, t2);
    float2 p1 = cadd(t1, t3), q1 = mul_i(csub(t1, t3), d);
    y[1] = cadd(p0, p1);
    y[3] = cadd(q0, q1);
}

// ---------- single radix-8 stages for conv (1 butterfly/thread, N=4096, NT=512) ----------
template <int HB, int DIR>
__device__ __forceinline__ void dif_stage(float2* s, int tid) {
    __syncthreads();
    const int h = 1 << HB;
    int j = tid & (h - 1);
    int base = ((tid >> HB) << (HB + 3)) + j;
    int s0 = swz(base);
    float2 x[8];
#pragma unroll
    for (int k = 0; k < 8; ++k) x[k] = s[s0 ^ swz(k << HB)];
    float2 y[8];
    dft8(x, y, (float)DIR);
    if constexpr (HB != 0) {
        float ang = (float)DIR * 6.283185307179586f / (float)(h << 3) * (float)j;
        float c, sn;
        __sincosf(ang, &sn, &c);
        float2 w = make_float2(c, sn), wm = w;
        s[s0] = y[0];
#pragma unroll
        for (int m = 1; m < 8; ++m) {
            s[s0 ^ swz(m << HB)] = cmul(wm, y[m]);
            wm = cmul(wm, w);
        }
    } else {  // j == 0 -> w == 1: no twiddles
#pragma unroll
        for (int m = 0; m < 8; ++m) s[s0 ^ swz(m << HB)] = y[m];
    }
}

template <int HB, int DIR>
__device__ __forceinline__ void dit_stage(float2* s, int tid) {
    __syncthreads();
    const int h = 1 << HB;
    int j = tid & (h - 1);
    int base = ((tid >> HB) << (HB + 3)) + j;
    int s0 = swz(base);
    float2 x[8];
    if constexpr (HB != 0) {
        float ang = (float)DIR * 6.283185307179586f / (float)(h << 3) * (float)j;
        float c, sn;
        __sincosf(ang, &sn, &c);
        float2 w = make_float2(c, sn);
        x[0] = s[s0];
        float2 wm = w;
#pragma unroll
        for (int k = 1; k < 8; ++k) {
            x[k] = cmul(wm, s[s0 ^ swz(k << HB)]);
            wm = cmul(wm, w);
        }
    } else {  // j == 0 -> no twiddles
#pragma unroll
        for (int k = 0; k < 8; ++k) x[k] = s[s0 ^ swz(k << HB)];
    }
    float2 y[8];
    dft8(x, y, (float)DIR);
#pragma unroll
    for (int m = 0; m < 8; ++m) s[s0 ^ swz(m << HB)] = y[m];
}

// ---------- generic radix-8 DIF (for kprep), with h=1 twiddle skip ----------
template <int LOGN, int NT>
__device__ void fft8_dif(float2* s, int tid, float dir) {
    const int N = 1 << LOGN;
#pragma unroll
    for (int hb = LOGN - 3; hb >= 0; hb -= 3) {
        const int h = 1 << hb;
        const float astep = dir * 6.283185307179586f / (float)(h << 3);
        __syncthreads();
#pragma unroll
        for (int it = 0; it < (N >> 3) / NT; ++it) {
            const int b = tid + it * NT;
            int j = b & (h - 1);
            int base = ((b >> hb) << (hb + 3)) + j;
            int s0 = swz(base);
            float2 x[8];
#pragma unroll
            for (int k = 0; k < 8; ++k) x[k] = s[s0 ^ swz(k << hb)];
            float2 y[8];
            dft8(x, y, dir);
            if (hb != 0) {  // folds: hb is unroll-constant
                float ang = astep * (float)j;
                float c, sn;
                __sincosf(ang, &sn, &c);
                float2 w = make_float2(c, sn), wm = w;
                s[s0] = y[0];
#pragma unroll
                for (int m = 1; m < 8; ++m) {
                    s[s0 ^ swz(m << hb)] = cmul(wm, y[m]);
                    wm = cmul(wm, w);
                }
            } else {
#pragma unroll
                for (int m = 0; m < 8; ++m) s[s0 ^ swz(m << hb)] = y[m];
            }
        }
    }
    __syncthreads();
}

// ---------- radix-2 DIF (unswizzled), for the 2048-pt kernel inverse only ----------
template <int LOGN, int NT>
__device__ void fft_dif2(float2* s, int tid, float dir) {
    const int N = 1 << LOGN;
    for (int st = LOGN - 1; st >= 0; --st) {
        __syncthreads();
        int half = 1 << st;
        for (int b = tid; b < (N >> 1); b += NT) {
            int j  = b & (half - 1);
            int i0 = ((b >> st) << (st + 1)) + j;
            int i1 = i0 + half;
            float2 u = s[i0], v = s[i1];
            float2 d = make_float2(u.x - v.x, u.y - v.y);
            s[i0] = make_float2(u.x + v.x, u.y + v.y);
            if (half > 1) {
                float ang = dir * 3.14159265358979f * (float)j / (float)half;
                float c, sn;
                __sincosf(ang, &sn, &c);
                s[i1] = cmul(make_float2(c, sn), d);
            } else {
                s[i1] = d;
            }
        }
    }
    __syncthreads();
}

// ---------- kernel A: k_f[h, f] via Cauchy + Woodbury, collapsed pair algebra ----------
__global__ __launch_bounds__(TPB) void kf_kernel(
    const float* __restrict__ log_dt, const float* __restrict__ w_ri,
    const float* __restrict__ Bri, const float* __restrict__ Cri,
    float2* __restrict__ kf) {
    __shared__ float2 wds[32];
    __shared__ float aab[4][32], rab[4][32];
    __shared__ float qn[32], pn[32];
    const int h   = blockIdx.x;
    const int tid = threadIdx.x;
    const float dt = expf(log_dt[h]);
    if (tid < 32) {
        float wr = w_ri[2 * tid] * dt, wi = w_ri[2 * tid + 1] * dt;
        wds[tid] = make_float2(wr, wi);
        qn[tid]  = wr * wr + wi * wi;
        pn[tid]  = -2.0f * wr;
    }
    __syncthreads();
    if (tid < 128) {
        int a = tid >> 6, b = (tid >> 5) & 1, n = tid & 31;
        const float* Cp = Cri + (((h * 2 + a) * 32) + n) * 2;
        const float* Bp = Bri + (((h * 2 + b) * 32) + n) * 2;
        float Cr = Cp[0], Ci = Cp[1], Br = Bp[0], Bi = Bp[1];
        float2 v = make_float2(Cr * Br + Ci * Bi, Cr * Bi - Ci * Br);  // conj(C)*B
        float2 wd = wds[n];
        aab[a * 2 + b][n] = -2.0f * (v.x * wd.x + v.y * wd.y);
        rab[a * 2 + b][n] = 2.0f * v.x;
    }
    __syncthreads();
    const int by   = blockIdx.y;
    const int fend = (by == 3) ? 2049 : (by + 1) * 512;
    for (int f = by * 512 + tid; f < fend; f += TPB) {
        float th = (6.283185307179586f / 4096.0f) * (float)f;
        float cf = cosf(th), sf = sinf(th);
        float2 den = make_float2(1.0f + cf, -sf);      // 1 + freq
        float zt  = 2.0f * tanf(0.5f * th);
        float zt2 = zt * zt;
        float2 r00 = make_float2(0.f, 0.f), r01 = r00, r10 = r00, r11 = r00;
        for (int n = 0; n < 32; ++n) {
            float c   = qn[n] - zt2;
            float d   = pn[n] * zt;
            float inv = 1.0f / (c * c + d * d);
            float cc = c * inv, dd = d * inv;
            float a0 = aab[0][n], b0 = rab[0][n] * zt;
            r00.x += a0 * cc + b0 * dd; r00.y += b0 * cc - a0 * dd;
            float a1 = aab[1][n], b1 = rab[1][n] * zt;
            r01.x += a1 * cc + b1 * dd; r01.y += b1 * cc - a1 * dd;
            float a2 = aab[2][n], b2 = rab[2][n] * zt;
            r10.x += a2 * cc + b2 * dd; r10.y += b2 * cc - a2 * dd;
            float a3 = aab[3][n], b3 = rab[3][n] * zt;
            r11.x += a3 * cc + b3 * dd; r11.y += b3 * cc - a3 * dd;
        }
        r00.x *= dt; r00.y *= dt; r01.x *= dt; r01.y *= dt;
        r10.x *= dt; r10.y *= dt; r11.x *= dt; r11.y *= dt;
        float2 q  = cdivf(cmul(r01, r10), make_float2(1.0f + r11.x, r11.y));
        float2 k0 = make_float2(r00.x - q.x, r00.y - q.y);
        float2 kv = cmul(k0, cdivf(make_float2(2.0f, 0.0f), den));
        kf[h * 2049 + f] = kv;
    }
}

// ---------- kernel B (fused): irfft_4096(k_f) -> zero-pad -> rfft_8192, store digit-rev
// with 1/4096 inverse-FFT scale pre-folded; row stride 4098 (16B-aligned rows) ----------
__global__ __launch_bounds__(KTPB) void kprep_kernel(const float2* __restrict__ kf,
                                                     float2* __restrict__ Kt) {
    __shared__ float2 s[4096];
    const int hh = blockIdx.x, tid = threadIdx.x;
    const float2* X = kf + hh * 2049;
    for (int m = tid; m < 2048; m += KTPB) {
        float2 Xm = X[m];
        float2 Xc = X[2048 - m];
        if (m == 0) { Xm.y = 0.0f; Xc.y = 0.0f; }
        float2 A  = make_float2(Xm.x + Xc.x, Xm.y - Xc.y);
        float2 Bv = make_float2(Xm.x - Xc.x, Xm.y + Xc.y);
        float ang = (3.14159265358979f / 2048.0f) * (float)m;
        float c, sn;
        __sincosf(ang, &sn, &c);
        float2 O = cmul(make_float2(c, sn), Bv);
        s[m] = make_float2(0.5f * (A.x - O.y), 0.5f * (A.y + O.x));
    }
    fft_dif2<11, KTPB>(s, tid, +1.0f);  // inverse, natural-in -> bitrev-out (unswizzled)
    float2 reg[4];
    const float sc = 1.0f / 2048.0f;
#pragma unroll
    for (int i = 0; i < 4; ++i) {
        int t = tid + KTPB * i;  // 0..2047
        float2 v = s[brev11(t)];
        reg[i] = make_float2(v.x * sc, v.y * sc);
    }
    __syncthreads();
#pragma unroll
    for (int i = 0; i < 4; ++i) {
        int t = tid + KTPB * i;
        s[swz(t)]        = reg[i];
        s[swz(t + 2048)] = make_float2(0.f, 0.f);
    }
    fft8_dif<12, KTPB>(s, tid, -1.0f);  // slot p holds Y[rev8(p)]
    float2* K = Kt + (size_t)hh * 4098;
    const float hsc = 0.5f / 4096.0f;   // unpack 1/2 * ifft 1/4096
    for (int p = tid; p < 4096; p += KTPB) {
        int j  = rev8(p);
        int jc = (4096 - j) & 4095;
        int pc = rev8(jc);
        float2 Yj = s[swz(p)], Yc = s[swz(pc)];
        float2 A  = make_float2(Yj.x + Yc.x, Yj.y - Yc.y);
        float2 Bv = make_float2(Yj.x - Yc.x, Yj.y + Yc.y);
        float ang = -(3.14159265358979f / 4096.0f) * (float)j;
        float c, sn;
        __sincosf(ang, &sn, &c);
        float2 t2 = cmul(make_float2(c, sn), make_float2(Bv.y, -Bv.x));
        K[p] = make_float2(hsc * (A.x + t2.x), hsc * (A.y + t2.y));
        if (p == 0) K[4096] = make_float2((2.0f * hsc) * (Yj.x - Yj.y), 0.0f);
    }
}

// ---------- transpose in: x[b,t,h] -> xt[(b*512+h), t], float4 both sides ----------
__global__ __launch_bounds__(TPB) void transpose_in(const float* __restrict__ x,
                                                    float* __restrict__ xt) {
    __shared__ float tile[64][65];
    const int b = blockIdx.z, t0 = blockIdx.y * 64, h0 = blockIdx.x * 64;
    const int tid = threadIdx.x;
    const float4* xv = (const float4*)(x + ((size_t)b * 4096 + t0) * 512 + h0);
#pragma unroll
    for (int i = 0; i < 4; ++i) {
        int idx = tid + TPB * i;       // 0..1023
        int tl = idx >> 4, hq = idx & 15;
        float4 v = xv[(size_t)tl * 128 + hq];
        tile[tl][hq * 4 + 0] = v.x; tile[tl][hq * 4 + 1] = v.y;
        tile[tl][hq * 4 + 2] = v.z; tile[tl][hq * 4 + 3] = v.w;
    }
    __syncthreads();
    float* xo = xt + ((size_t)(b * 512 + h0)) * 4096 + t0;
#pragma unroll
    for (int i = 0; i < 4; ++i) {
        int idx = tid + TPB * i;
        int hl = idx >> 4, tq = idx & 15;
        float4 v = make_float4(tile[tq * 4 + 0][hl], tile[tq * 4 + 1][hl],
                               tile[tq * 4 + 2][hl], tile[tq * 4 + 3][hl]);
        ((float4*)(xo + (size_t)hl * 4096))[tq] = v;
    }
}

// ---------- pointwise pair op: both sides of 4 Hermitian pairs of owner block tb ----------
//   pair {p, pc}, j = rev8(p):  Z'_p  = P*Z_p + Q*conj(Z_pc)
//                               Z'_pc = P'*Z_pc - conj(Q)*conj(Z_p)      [conj(Q)!]
//   P  = az*Kj + bz*conj(Kc), P' = az*Kc + bz*conj(Kj), Q = (i*cth/2)(Kj - conj(Kc))
//   az = (1-sth)/2, bz = (1+sth)/2, θ = πj/4096 = πk/8 + πJb/4096.
//   Jb==0 block: k=0 is DC/Nyquist combo (Kc = K[4096]), k=4 self-pair; the double
//   writes are value-identical (verified symbolically under the conj(Q) form).
__device__ __forceinline__ void pq_pairs(float2* s, const float2* __restrict__ Krow,
                                         int tb, int half) {
    const int p0  = tb << 3;
    const int sp0 = swz(p0);
    const int Jb  = ((tb & 7) << 6) | (tb & 56) | (tb >> 6);  // rev8(p0)
    const int RM  = rev8(512 - Jb);                           // partner slot base (Jb!=0)
    float sphi, cphi;
    __sincosf((3.14159265358979f / 4096.0f) * (float)Jb, &sphi, &cphi);
#pragma unroll
    for (int kk = 0; kk < 4; ++kk) {
        const int k   = (half << 2) | kk;
        const int pck = Jb ? (RM | (7 - k)) : ((8 - k) & 7);
        const int spc = swz(pck);
        float2 z  = s[sp0 ^ k];
        float2 zc = s[spc];
        float2 Kj = Krow[p0 + k];
        float2 Kc = Krow[(Jb | k) ? pck : 4096];
        // sin/cos(pi*k/8) via half-select of compile-time constants (no array idx)
        const float SKk = (kk == 0) ? 0.0f : (kk == 1) ? 0.3826834324f
                          : (kk == 2) ? 0.7071067812f : 0.9238795325f;
        const float CKk = (kk == 0) ? 1.0f : (kk == 1) ? 0.9238795325f
                          : (kk == 2) ? 0.7071067812f : 0.3826834324f;
        float skk = half ? CKk : SKk;
        float ckk = half ? -SKk : CKk;
        float sth = skk * cphi + ckk * sphi;      // sin(θ)
        float cth = ckk * cphi - skk * sphi;      // cos(θ)
        float az = 0.5f * (1.0f - sth), bz = 0.5f * (1.0f + sth), hc = 0.5f * cth;
        float Px  = az * Kj.x + bz * Kc.x, Py  = az * Kj.y - bz * Kc.y;
        float Qx  = -hc * (Kj.y + Kc.y),   Qy  = hc * (Kj.x - Kc.x);
        float Ppx = az * Kc.x + bz * Kj.x, Ppy = az * Kc.y - bz * Kj.y;
        // own:     P*z + Q*conj(zc)
        s[sp0 ^ k] = make_float2(Px * z.x - Py * z.y + Qx * zc.x + Qy * zc.y,
                                 Px * z.y + Py * z.x + Qy * zc.x - Qx * zc.y);
        // partner: P'*zc - conj(Q)*conj(z)
        s[spc]     = make_float2(Ppx * zc.x - Ppy * zc.y - Qx * z.x + Qy * z.y,
                                 Ppx * zc.y + Ppy * zc.x + Qx * z.y + Qy * z.x);
    }
}

// ---------- fused conv: y = irfft8192(rfft8192(x)*K~)[0:4096] + D*x, radix-8,
// reg end-stages; Hermitian pointwise as uniform pair-owner P/Q linear map.
//   Owner blocks = {t : t&4==0} (Jb<256); partner blocks Jb'=512-Jb are covered by the
//   owners' partner writes. Block t=4 (Jb=256) is its OWN partner (not in either set):
//   threads 0,1 run a second predicated pass over it; its internal double-writes agree
//   numerically. Threads (2v,2v+1) split block v's 8 pairs -> all 512 threads busy,
//   in-place LDS writes, no extra barrier, no cross-barrier registers. ----------
__global__ __launch_bounds__(CTPB) void conv_kernel(const float* xt,
                                                    const float2* __restrict__ Kt,
                                                    const float* __restrict__ Dv,
                                                    float* yt) {
    __shared__ float2 s[4096];
    const int row = blockIdx.x, tid = threadIdx.x;
    const int hch = row & 511;
    const int stid = swz(tid);
    const float2* xr = (const float2*)(xt + (size_t)row * 4096);

    // ---- D1 (DIF h=512) in registers; upper half is the zero pad -> dft8z
    {
        float2 x0 = xr[tid], x1 = xr[tid + 512], x2 = xr[tid + 1024], x3 = xr[tid + 1536];
        float2 y[8];
        dft8z(x0, x1, x2, x3, y, -1.0f);
        float ang = -(6.283185307179586f / 4096.0f) * (float)tid;
        float c, sn;
        __sincosf(ang, &sn, &c);
        float2 w = make_float2(c, sn), wm = w;
        s[stid] = y[0];
#pragma unroll
        for (int m = 1; m < 8; ++m) {
            s[stid ^ swz(m << 9)] = cmul(wm, y[m]);
            wm = cmul(wm, w);
        }
    }
    dif_stage<6, -1>(s, tid);
    dif_stage<3, -1>(s, tid);
    dif_stage<0, -1>(s, tid);
    // ---- pointwise: uniform pair-owner P/Q (in place, one barrier before)
    {
        const int o    = tid >> 1, half = tid & 1;
        const int t0i  = ((o & ~3) << 1) | (o & 3);   // owner block index (bit2==0)
        const float2* Krow = Kt + (size_t)hch * 4098;
        __syncthreads();                              // dif<0> writes visible
        pq_pairs(s, Krow, t0i, half);
        if (o == 0) pq_pairs(s, Krow, 4, half);       // self-partner block Jb=256
    }
    dit_stage<0, 1>(s, tid);
    dit_stage<3, 1>(s, tid);
    dit_stage<6, 1>(s, tid);
    __syncthreads();
    // ---- I4 (DIT h=512) in registers; keep only first 4096 samples; fuse D*x skip
    // (1/4096 inverse scale pre-folded into Kt by kprep)
    {
        float ang = (6.283185307179586f / 4096.0f) * (float)tid;
        float c, sn;
        __sincosf(ang, &sn, &c);
        float2 w = make_float2(c, sn);
        float2 x[8];
        x[0] = s[stid];
        float2 wm = w;
#pragma unroll
        for (int k = 1; k < 8; ++k) {
            x[k] = cmul(wm, s[stid ^ swz(k << 9)]);
            wm = cmul(wm, w);
        }
        float2 y[4];
        dft8_lo(x, y, 1.0f);
        const float D = Dv[hch];
        float2* yo = (float2*)(yt + (size_t)row * 4096);
#pragma unroll
        for (int m = 0; m < 4; ++m) {
            int t2 = tid + (m << 9);
            float2 xin = xr[t2];  // re-read own row (L2-warm); xt/yt alias is per-element safe
            yo[t2] = make_float2(y[m].x + D * xin.x, y[m].y + D * xin.y);
        }
    }
}

// ---------- transpose out (pure): out[b,t,h] = yt[(b*512+h),t] ----------
__global__ __launch_bounds__(TPB) void transpose_out(const float* __restrict__ yt,
                                                     float* __restrict__ out) {
    __shared__ float tile[64][65];
    const int b = blockIdx.z, t0 = blockIdx.y * 64, h0 = blockIdx.x * 64;
    const int tid = threadIdx.x;
    const float* yp = yt + ((size_t)(b * 512 + h0)) * 4096 + t0;
#pragma unroll
    for (int i = 0; i < 4; ++i) {
        int idx = tid + TPB * i;
        int hl = idx >> 4, tq = idx & 15;
        float4 v = ((const float4*)(yp + (size_t)hl * 4096))[tq];
        tile[tq * 4 + 0][hl] = v.x; tile[tq * 4 + 1][hl] = v.y;
        tile[tq * 4 + 2][hl] = v.z; tile[tq * 4 + 3][hl] = v.w;
    }
    __syncthreads();
    float4* ov = (float4*)(out + ((size_t)b * 4096 + t0) * 512 + h0);
#pragma unroll
    for (int i = 0; i < 4; ++i) {
        int idx = tid + TPB * i;
        int tl = idx >> 4, hq = idx & 15;
        float4 v = make_float4(tile[tl][4 * hq + 0], tile[tl][4 * hq + 1],
                               tile[tl][4 * hq + 2], tile[tl][4 * hq + 3]);
        ov[(size_t)tl * 128 + hq] = v;
    }
}

extern "C" void kernel_launch(void* const* d_in, const int* in_sizes, int n_in,
                              void* d_out, int out_size, void* d_ws, size_t ws_size,
                              hipStream_t stream) {
    (void)in_sizes; (void)n_in; (void)out_size; (void)ws_size;
    const float* x      = (const float*)d_in[0];  // [8,4096,512]
    const float* log_dt = (const float*)d_in[1];  // [512]
    const float* w_ri   = (const float*)d_in[2];  // [32,2]
    const float* Bri    = (const float*)d_in[3];  // [512,2,32,2]
    const float* Cri    = (const float*)d_in[4];  // [512,2,32,2]
    const float* Dv     = (const float*)d_in[5];  // [512]
    float* out = (float*)d_out;

    char* ws = (char*)d_ws;
    // Layout (stream order makes the alias safe):
    //   kf aliases xt[0:8.4MB) — written by kf_kernel, fully consumed by kprep_kernel
    //   BEFORE transpose_in overwrites xt.  xt reused as yt by conv (in-place).
    float*  xt = (float*)(ws);                  // 8*512*4096*4 = 67,108,864 B
    float2* kf = (float2*)(ws);                 // 512*2049*8   =  8,392,704 B (aliased)
    float2* Kt = (float2*)(ws + 67108864);      // 512*4098*8   = 16,785,408 B (end ~83.9 MB)

    kf_kernel<<<dim3(512, 4), TPB, 0, stream>>>(log_dt, w_ri, Bri, Cri, kf);
    kprep_kernel<<<512, KTPB, 0, stream>>>(kf, Kt);
    transpose_in<<<dim3(8, 64, 8), TPB, 0, stream>>>(x, xt);
    conv_kernel<<<4096, CTPB, 0, stream>>>(xt, Kt, Dv, xt);  // y(+skip) overwrites xt rows
    transpose_out<<<dim3(8, 64, 8), TPB, 0, stream>>>(xt, out);
}

// Round 6
// 277.101 us; speedup vs baseline: 1.3785x; 1.0616x over previous
//
#include <hip/hip_runtime.h>
#include <math.h>

#define TPB 256
#define CTPB 512
#define KTPB 512

// ---------- complex helpers ----------
__device__ __forceinline__ float2 cmul(float2 a, float2 b) {
    return make_float2(a.x * b.x - a.y * b.y, a.x * b.y + a.y * b.x);
}
__device__ __forceinline__ float2 cdivf(float2 a, float2 b) {
    float inv = 1.0f / (b.x * b.x + b.y * b.y);
    return make_float2((a.x * b.x + a.y * b.y) * inv, (a.y * b.x - a.x * b.y) * inv);
}
__device__ __forceinline__ float2 cadd(float2 a, float2 b) { return make_float2(a.x + b.x, a.y + b.y); }
__device__ __forceinline__ float2 csub(float2 a, float2 b) { return make_float2(a.x - b.x, a.y - b.y); }
__device__ __forceinline__ float2 mul_i(float2 a, float d) {  // a * (i*d)
    return make_float2(-d * a.y, d * a.x);
}
__device__ __forceinline__ int brev11(int x) { return (int)(__brev((unsigned)x) >> 21); }
// base-8 digit reversal of a 12-bit index (4 digits)
__device__ __forceinline__ int rev8(int x) {
    return ((x & 7) << 9) | (((x >> 3) & 7) << 6) | (((x >> 6) & 7) << 3) | ((x >> 9) & 7);
}
// LDS bank swizzle. GF(2)-LINEAR: swz(a^b) == swz(a)^swz(b) -> per-tap offsets fold
// to compile-time XOR constants.
__device__ __forceinline__ int swz(int i) { return i ^ ((i >> 4) & 15) ^ ((i >> 8) & 15); }

// ---------- 8-point DFT cores ----------
__device__ __forceinline__ void dft8(const float2* x, float2* y, float d) {
    const float r = 0.70710678118f;
    float2 s0 = cadd(x[0], x[4]), t0 = csub(x[0], x[4]);
    float2 s1 = cadd(x[1], x[5]), t1 = csub(x[1], x[5]);
    float2 s2 = cadd(x[2], x[6]), t2 = csub(x[2], x[6]);
    float2 s3 = cadd(x[3], x[7]), t3 = csub(x[3], x[7]);
    t1 = cmul(t1, make_float2(r, d * r));
    t2 = mul_i(t2, d);
    t3 = cmul(t3, make_float2(-r, d * r));
    float2 u0 = cadd(s0, s2), v0 = csub(s0, s2);
    float2 u1 = cadd(s1, s3), v1 = mul_i(csub(s1, s3), d);
    y[0] = cadd(u0, u1); y[4] = csub(u0, u1);
    y[2] = cadd(v0, v1); y[6] = csub(v0, v1);
    float2 p0 = cadd(t0, t2), q0 = csub(t0, t2);
    float2 p1 = cadd(t1, t3), q1 = mul_i(csub(t1, t3), d);
    y[1] = cadd(p0, p1); y[5] = csub(p0, p1);
    y[3] = cadd(q0, q1); y[7] = csub(q0, q1);
}

// dft8 with x[4..7] == 0 (zero-padded upper half): level 1 vanishes (s_i = t_i = x_i)
__device__ __forceinline__ void dft8z(float2 x0, float2 x1, float2 x2, float2 x3,
                                      float2* y, float d) {
    const float r = 0.70710678118f;
    float2 u0 = cadd(x0, x2), v0 = csub(x0, x2);
    float2 u1 = cadd(x1, x3), v1 = mul_i(csub(x1, x3), d);
    float2 t1 = cmul(x1, make_float2(r, d * r));
    float2 t2 = mul_i(x2, d);
    float2 t3 = cmul(x3, make_float2(-r, d * r));
    float2 p0 = cadd(x0, t2), q0 = csub(x0, t2);
    float2 p1 = cadd(t1, t3), q1 = mul_i(csub(t1, t3), d);
    y[0] = cadd(u0, u1); y[4] = csub(u0, u1);
    y[2] = cadd(v0, v1); y[6] = csub(v0, v1);
    y[1] = cadd(p0, p1); y[5] = csub(p0, p1);
    y[3] = cadd(q0, q1); y[7] = csub(q0, q1);
}

// dft8 computing only outputs y[0..3] (the '+' halves) — for the discarded tail
__device__ __forceinline__ void dft8_lo(const float2* x, float2* y, float d) {
    const float r = 0.70710678118f;
    float2 s0 = cadd(x[0], x[4]), t0 = csub(x[0], x[4]);
    float2 s1 = cadd(x[1], x[5]), t1 = csub(x[1], x[5]);
    float2 s2 = cadd(x[2], x[6]), t2 = csub(x[2], x[6]);
    float2 s3 = cadd(x[3], x[7]), t3 = csub(x[3], x[7]);
    t1 = cmul(t1, make_float2(r, d * r));
    t2 = mul_i(t2, d);
    t3 = cmul(t3, make_float2(-r, d * r));
    float2 u0 = cadd(s0, s2), v0 = csub(s0, s2);
    float2 u1 = cadd(s1, s3), v1 = mul_i(csub(s1, s3), d);
    y[0] = cadd(u0, u1);
    y[2] = cadd(v0, v1);
    float2 p0 = cadd(t0, t2), q0 = csub(t0, t2);
    float2 p1 = cadd(t1, t3), q1 = mul_i(csub(t1, t3), d);
    y[1] = cadd(p0, p1);
    y[3] = cadd(q0, q1);
}

// ---------- single radix-8 stages for conv (1 butterfly/thread, N=4096, NT=512) ----------
template <int HB, int DIR>
__device__ __forceinline__ void dif_stage(float2* s, int tid) {
    __syncthreads();
    const int h = 1 << HB;
    int j = tid & (h - 1);
    int base = ((tid >> HB) << (HB + 3)) + j;
    int s0 = swz(base);
    float2 x[8];
#pragma unroll
    for (int k = 0; k < 8; ++k) x[k] = s[s0 ^ swz(k << HB)];
    float2 y[8];
    dft8(x, y, (float)DIR);
    if constexpr (HB != 0) {
        float ang = (float)DIR * 6.283185307179586f / (float)(h << 3) * (float)j;
        float c, sn;
        __sincosf(ang, &sn, &c);
        float2 w = make_float2(c, sn), wm = w;
        s[s0] = y[0];
#pragma unroll
        for (int m = 1; m < 8; ++m) {
            s[s0 ^ swz(m << HB)] = cmul(wm, y[m]);
            wm = cmul(wm, w);
        }
    } else {  // j == 0 -> w == 1: no twiddles
#pragma unroll
        for (int m = 0; m < 8; ++m) s[s0 ^ swz(m << HB)] = y[m];
    }
}

template <int HB, int DIR>
__device__ __forceinline__ void dit_stage(float2* s, int tid) {
    __syncthreads();
    const int h = 1 << HB;
    int j = tid & (h - 1);
    int base = ((tid >> HB) << (HB + 3)) + j;
    int s0 = swz(base);
    float2 x[8];
    if constexpr (HB != 0) {
        float ang = (float)DIR * 6.283185307179586f / (float)(h << 3) * (float)j;
        float c, sn;
        __sincosf(ang, &sn, &c);
        float2 w = make_float2(c, sn);
        x[0] = s[s0];
        float2 wm = w;
#pragma unroll
        for (int k = 1; k < 8; ++k) {
            x[k] = cmul(wm, s[s0 ^ swz(k << HB)]);
            wm = cmul(wm, w);
        }
    } else {  // j == 0 -> no twiddles
#pragma unroll
        for (int k = 0; k < 8; ++k) x[k] = s[s0 ^ swz(k << HB)];
    }
    float2 y[8];
    dft8(x, y, (float)DIR);
#pragma unroll
    for (int m = 0; m < 8; ++m) s[s0 ^ swz(m << HB)] = y[m];
}

// ---------- generic radix-8 DIF (for kprep), with h=1 twiddle skip ----------
template <int LOGN, int NT>
__device__ void fft8_dif(float2* s, int tid, float dir) {
    const int N = 1 << LOGN;
#pragma unroll
    for (int hb = LOGN - 3; hb >= 0; hb -= 3) {
        const int h = 1 << hb;
        const float astep = dir * 6.283185307179586f / (float)(h << 3);
        __syncthreads();
#pragma unroll
        for (int it = 0; it < (N >> 3) / NT; ++it) {
            const int b = tid + it * NT;
            int j = b & (h - 1);
            int base = ((b >> hb) << (hb + 3)) + j;
            int s0 = swz(base);
            float2 x[8];
#pragma unroll
            for (int k = 0; k < 8; ++k) x[k] = s[s0 ^ swz(k << hb)];
            float2 y[8];
            dft8(x, y, dir);
            if (hb != 0) {  // folds: hb is unroll-constant
                float ang = astep * (float)j;
                float c, sn;
                __sincosf(ang, &sn, &c);
                float2 w = make_float2(c, sn), wm = w;
                s[s0] = y[0];
#pragma unroll
                for (int m = 1; m < 8; ++m) {
                    s[s0 ^ swz(m << hb)] = cmul(wm, y[m]);
                    wm = cmul(wm, w);
                }
            } else {
#pragma unroll
                for (int m = 0; m < 8; ++m) s[s0 ^ swz(m << hb)] = y[m];
            }
        }
    }
    __syncthreads();
}

// ---------- radix-2 DIF (unswizzled), for the 2048-pt kernel inverse only ----------
template <int LOGN, int NT>
__device__ void fft_dif2(float2* s, int tid, float dir) {
    const int N = 1 << LOGN;
    for (int st = LOGN - 1; st >= 0; --st) {
        __syncthreads();
        int half = 1 << st;
        for (int b = tid; b < (N >> 1); b += NT) {
            int j  = b & (half - 1);
            int i0 = ((b >> st) << (st + 1)) + j;
            int i1 = i0 + half;
            float2 u = s[i0], v = s[i1];
            float2 d = make_float2(u.x - v.x, u.y - v.y);
            s[i0] = make_float2(u.x + v.x, u.y + v.y);
            if (half > 1) {
                float ang = dir * 3.14159265358979f * (float)j / (float)half;
                float c, sn;
                __sincosf(ang, &sn, &c);
                s[i1] = cmul(make_float2(c, sn), d);
            } else {
                s[i1] = d;
            }
        }
    }
    __syncthreads();
}

// ---------- kernel A+B fused: Cauchy/Woodbury k_f (into LDS) -> irfft_4096 ->
// zero-pad -> rfft_8192, store digit-rev.  kf spectrum never touches HBM. ----------
__global__ __launch_bounds__(KTPB) void kprep_kernel(
    const float* __restrict__ log_dt, const float* __restrict__ w_ri,
    const float* __restrict__ Bri, const float* __restrict__ Cri,
    float2* __restrict__ Kt) {
    __shared__ float2 s[4096];
    __shared__ float2 kfs[2049];
    __shared__ float2 wds[32];
    __shared__ float aab[4][32], rab[4][32];
    __shared__ float qn[32], pn[32];
    const int hh = blockIdx.x, tid = threadIdx.x;

    // ---- kf part (identical math to the former kf_kernel, f-range = full 2049)
    const float dt = expf(log_dt[hh]);
    if (tid < 32) {
        float wr = w_ri[2 * tid] * dt, wi = w_ri[2 * tid + 1] * dt;
        wds[tid] = make_float2(wr, wi);
        qn[tid]  = wr * wr + wi * wi;
        pn[tid]  = -2.0f * wr;
    }
    __syncthreads();
    if (tid < 128) {
        int a = tid >> 6, b = (tid >> 5) & 1, n = tid & 31;
        const float* Cp = Cri + (((hh * 2 + a) * 32) + n) * 2;
        const float* Bp = Bri + (((hh * 2 + b) * 32) + n) * 2;
        float Cr = Cp[0], Ci = Cp[1], Br = Bp[0], Bi = Bp[1];
        float2 v = make_float2(Cr * Br + Ci * Bi, Cr * Bi - Ci * Br);  // conj(C)*B
        float2 wd = wds[n];
        aab[a * 2 + b][n] = -2.0f * (v.x * wd.x + v.y * wd.y);
        rab[a * 2 + b][n] = 2.0f * v.x;
    }
    __syncthreads();
    for (int f = tid; f < 2049; f += KTPB) {
        float th = (6.283185307179586f / 4096.0f) * (float)f;
        float cf = cosf(th), sf = sinf(th);
        float2 den = make_float2(1.0f + cf, -sf);      // 1 + freq
        float zt  = 2.0f * tanf(0.5f * th);
        float zt2 = zt * zt;
        float2 r00 = make_float2(0.f, 0.f), r01 = r00, r10 = r00, r11 = r00;
        for (int n = 0; n < 32; ++n) {
            float c   = qn[n] - zt2;
            float d   = pn[n] * zt;
            float inv = 1.0f / (c * c + d * d);
            float cc = c * inv, dd = d * inv;
            float a0 = aab[0][n], b0 = rab[0][n] * zt;
            r00.x += a0 * cc + b0 * dd; r00.y += b0 * cc - a0 * dd;
            float a1 = aab[1][n], b1 = rab[1][n] * zt;
            r01.x += a1 * cc + b1 * dd; r01.y += b1 * cc - a1 * dd;
            float a2 = aab[2][n], b2 = rab[2][n] * zt;
            r10.x += a2 * cc + b2 * dd; r10.y += b2 * cc - a2 * dd;
            float a3 = aab[3][n], b3 = rab[3][n] * zt;
            r11.x += a3 * cc + b3 * dd; r11.y += b3 * cc - a3 * dd;
        }
        r00.x *= dt; r00.y *= dt; r01.x *= dt; r01.y *= dt;
        r10.x *= dt; r10.y *= dt; r11.x *= dt; r11.y *= dt;
        float2 q  = cdivf(cmul(r01, r10), make_float2(1.0f + r11.x, r11.y));
        float2 k0 = make_float2(r00.x - q.x, r00.y - q.y);
        float2 kv = cmul(k0, cdivf(make_float2(2.0f, 0.0f), den));
        kfs[f] = kv;
    }
    __syncthreads();

    // ---- kprep part (identical to r0, X read from LDS instead of global)
    const float2* X = kfs;
    for (int m = tid; m < 2048; m += KTPB) {
        float2 Xm = X[m];
        float2 Xc = X[2048 - m];
        if (m == 0) { Xm.y = 0.0f; Xc.y = 0.0f; }
        float2 A  = make_float2(Xm.x + Xc.x, Xm.y - Xc.y);
        float2 Bv = make_float2(Xm.x - Xc.x, Xm.y + Xc.y);
        float ang = (3.14159265358979f / 2048.0f) * (float)m;
        float c, sn;
        __sincosf(ang, &sn, &c);
        float2 O = cmul(make_float2(c, sn), Bv);
        s[m] = make_float2(0.5f * (A.x - O.y), 0.5f * (A.y + O.x));
    }
    fft_dif2<11, KTPB>(s, tid, +1.0f);  // inverse, natural-in -> bitrev-out (unswizzled)
    float2 reg[4];
    const float sc = 1.0f / 2048.0f;
#pragma unroll
    for (int i = 0; i < 4; ++i) {
        int t = tid + KTPB * i;  // 0..2047
        float2 v = s[brev11(t)];
        reg[i] = make_float2(v.x * sc, v.y * sc);
    }
    __syncthreads();
#pragma unroll
    for (int i = 0; i < 4; ++i) {
        int t = tid + KTPB * i;
        s[swz(t)]        = reg[i];
        s[swz(t + 2048)] = make_float2(0.f, 0.f);
    }
    fft8_dif<12, KTPB>(s, tid, -1.0f);  // slot p holds Y[rev8(p)]
    float2* K = Kt + (size_t)hh * 4097;
    for (int p = tid; p < 4096; p += KTPB) {
        int j  = rev8(p);
        int jc = (4096 - j) & 4095;
        int pc = rev8(jc);
        float2 Yj = s[swz(p)], Yc = s[swz(pc)];
        float2 A  = make_float2(Yj.x + Yc.x, Yj.y - Yc.y);
        float2 Bv = make_float2(Yj.x - Yc.x, Yj.y + Yc.y);
        float ang = -(3.14159265358979f / 4096.0f) * (float)j;
        float c, sn;
        __sincosf(ang, &sn, &c);
        float2 t2 = cmul(make_float2(c, sn), make_float2(Bv.y, -Bv.x));
        K[p] = make_float2(0.5f * (A.x + t2.x), 0.5f * (A.y + t2.y));
        if (p == 0) K[4096] = make_float2(Yj.x - Yj.y, 0.0f);
    }
}

// ---------- transpose in: x[b,t,h] -> xt[(b*512+h), t], float4 both sides ----------
__global__ __launch_bounds__(TPB) void transpose_in(const float* __restrict__ x,
                                                    float* __restrict__ xt) {
    __shared__ float tile[64][65];
    const int b = blockIdx.z, t0 = blockIdx.y * 64, h0 = blockIdx.x * 64;
    const int tid = threadIdx.x;
    const float4* xv = (const float4*)(x + ((size_t)b * 4096 + t0) * 512 + h0);
#pragma unroll
    for (int i = 0; i < 4; ++i) {
        int idx = tid + TPB * i;       // 0..1023
        int tl = idx >> 4, hq = idx & 15;
        float4 v = xv[(size_t)tl * 128 + hq];
        tile[tl][hq * 4 + 0] = v.x; tile[tl][hq * 4 + 1] = v.y;
        tile[tl][hq * 4 + 2] = v.z; tile[tl][hq * 4 + 3] = v.w;
    }
    __syncthreads();
    float* xo = xt + ((size_t)(b * 512 + h0)) * 4096 + t0;
#pragma unroll
    for (int i = 0; i < 4; ++i) {
        int idx = tid + TPB * i;
        int hl = idx >> 4, tq = idx & 15;
        float4 v = make_float4(tile[tq * 4 + 0][hl], tile[tq * 4 + 1][hl],
                               tile[tq * 4 + 2][hl], tile[tq * 4 + 3][hl]);
        ((float4*)(xo + (size_t)hl * 4096))[tq] = v;
    }
}

// ---------- fused conv: y = irfft8192(rfft8192(x)*K~)[0:4096]*1 + D*x, radix-8, reg end-stages ----------
__global__ __launch_bounds__(CTPB) void conv_kernel(const float* xt,
                                                    const float2* __restrict__ Kt,
                                                    const float* __restrict__ Dv,
                                                    float* yt) {
    __shared__ float2 s[4096];
    const int row = blockIdx.x, tid = threadIdx.x;
    const int hch = row & 511;
    const int stid = swz(tid);
    const float2* xr = (const float2*)(xt + (size_t)row * 4096);

    // ---- D1 (DIF h=512) in registers; upper half is the zero pad -> dft8z
    {
        float2 x0 = xr[tid], x1 = xr[tid + 512], x2 = xr[tid + 1024], x3 = xr[tid + 1536];
        float2 y[8];
        dft8z(x0, x1, x2, x3, y, -1.0f);
        float ang = -(6.283185307179586f / 4096.0f) * (float)tid;
        float c, sn;
        __sincosf(ang, &sn, &c);
        float2 w = make_float2(c, sn), wm = w;
        s[stid] = y[0];
#pragma unroll
        for (int m = 1; m < 8; ++m) {
            s[stid ^ swz(m << 9)] = cmul(wm, y[m]);
            wm = cmul(wm, w);
        }
    }
    dif_stage<6, -1>(s, tid);
    dif_stage<3, -1>(s, tid);
    dif_stage<0, -1>(s, tid);
    __syncthreads();
    // ---- pointwise multiply in digit-reversed Hermitian-packed domain
    const float2* K = Kt + (size_t)hch * 4097;
#pragma unroll
    for (int i = 0; i < 8; ++i) {
        int p  = tid + CTPB * i;
        int sp = stid ^ swz(CTPB * i);
        if (p == 0) {  // j=0 pairs with bin 4096
            float2 Y0 = s[sp];
            float X0 = Y0.x + Y0.y;
            float Xn = Y0.x - Y0.y;
            float Z0 = X0 * K[0].x;
            float Zn = Xn * K[4096].x;
            s[sp] = make_float2(0.5f * (Z0 + Zn), 0.5f * (Z0 - Zn));
            continue;
        }
        int j  = rev8(p);
        int jc = 4096 - j;
        int pc = rev8(jc & 4095);
        if (pc < p) continue;  // pair owner has the smaller slot
        float2 Yj = s[sp], Yc = s[swz(pc)];
        float2 A  = make_float2(Yj.x + Yc.x, Yj.y - Yc.y);
        float2 Bv = make_float2(Yj.x - Yc.x, Yj.y + Yc.y);
        float ang = -(3.14159265358979f / 4096.0f) * (float)j;
        float c, sn;
        __sincosf(ang, &sn, &c);
        float2 W = make_float2(c, sn);
        float2 t2 = cmul(W, make_float2(Bv.y, -Bv.x));
        float2 Xj = make_float2(0.5f * (A.x + t2.x), 0.5f * (A.y + t2.y));
        float2 t2c = cmul(make_float2(-W.x, W.y), make_float2(Bv.y, Bv.x));
        float2 Xc2 = make_float2(0.5f * (A.x + t2c.x), 0.5f * (-A.y + t2c.y));
        float2 Zj = cmul(Xj, K[p]);
        float2 Zc = cmul(Xc2, K[pc]);
        float2 A2 = make_float2(Zj.x + Zc.x, Zj.y - Zc.y);
        float2 B2 = make_float2(Zj.x - Zc.x, Zj.y + Zc.y);
        float2 O2 = cmul(make_float2(W.x, -W.y), B2);
        s[sp] = make_float2(0.5f * (A2.x - O2.y), 0.5f * (A2.y + O2.x));
        if (pc != p) {
            float2 O2c = cmul(make_float2(-W.x, -W.y), make_float2(-B2.x, B2.y));
            s[swz(pc)] = make_float2(0.5f * (A2.x - O2c.y), 0.5f * (-A2.y + O2c.x));
        }
    }
    dit_stage<0, 1>(s, tid);
    dit_stage<3, 1>(s, tid);
    dit_stage<6, 1>(s, tid);
    __syncthreads();
    // ---- I4 (DIT h=512) in registers; keep only first 4096 samples; fuse D*x skip
    {
        float ang = (6.283185307179586f / 4096.0f) * (float)tid;
        float c, sn;
        __sincosf(ang, &sn, &c);
        float2 w = make_float2(c, sn);
        float2 x[8];
        x[0] = s[stid];
        float2 wm = w;
#pragma unroll
        for (int k = 1; k < 8; ++k) {
            x[k] = cmul(wm, s[stid ^ swz(k << 9)]);
            wm = cmul(wm, w);
        }
        float2 y[4];
        dft8_lo(x, y, 1.0f);
        const float D = Dv[hch];
        float2* yo = (float2*)(yt + (size_t)row * 4096);
        const float sc = 1.0f / 4096.0f;
#pragma unroll
        for (int m = 0; m < 4; ++m) {
            int t2 = tid + (m << 9);
            float2 xin = xr[t2];  // re-read own row (L2-warm); xt/yt alias is per-element safe
            yo[t2] = make_float2(y[m].x * sc + D * xin.x, y[m].y * sc + D * xin.y);
        }
    }
}

// ---------- transpose out (pure): out[b,t,h] = yt[(b*512+h),t] ----------
__global__ __launch_bounds__(TPB) void transpose_out(const float* __restrict__ yt,
                                                     float* __restrict__ out) {
    __shared__ float tile[64][65];
    const int b = blockIdx.z, t0 = blockIdx.y * 64, h0 = blockIdx.x * 64;
    const int tid = threadIdx.x;
    const float* yp = yt + ((size_t)(b * 512 + h0)) * 4096 + t0;
#pragma unroll
    for (int i = 0; i < 4; ++i) {
        int idx = tid + TPB * i;
        int hl = idx >> 4, tq = idx & 15;
        float4 v = ((const float4*)(yp + (size_t)hl * 4096))[tq];
        tile[tq * 4 + 0][hl] = v.x; tile[tq * 4 + 1][hl] = v.y;
        tile[tq * 4 + 2][hl] = v.z; tile[tq * 4 + 3][hl] = v.w;
    }
    __syncthreads();
    float4* ov = (float4*)(out + ((size_t)b * 4096 + t0) * 512 + h0);
#pragma unroll
    for (int i = 0; i < 4; ++i) {
        int idx = tid + TPB * i;
        int tl = idx >> 4, hq = idx & 15;
        float4 v = make_float4(tile[tl][4 * hq + 0], tile[tl][4 * hq + 1],
                               tile[tl][4 * hq + 2], tile[tl][4 * hq + 3]);
        ov[(size_t)tl * 128 + hq] = v;
    }
}

extern "C" void kernel_launch(void* const* d_in, const int* in_sizes, int n_in,
                              void* d_out, int out_size, void* d_ws, size_t ws_size,
                              hipStream_t stream) {
    (void)in_sizes; (void)n_in; (void)out_size; (void)ws_size;
    const float* x      = (const float*)d_in[0];  // [8,4096,512]
    const float* log_dt = (const float*)d_in[1];  // [512]
    const float* w_ri   = (const float*)d_in[2];  // [32,2]
    const float* Bri    = (const float*)d_in[3];  // [512,2,32,2]
    const float* Cri    = (const float*)d_in[4];  // [512,2,32,2]
    const float* Dv     = (const float*)d_in[5];  // [512]
    float* out = (float*)d_out;

    char* ws = (char*)d_ws;
    float*  xt = (float*)(ws);                  // 8*512*4096*4 = 67,108,864 B (reused as yt)
    float2* Kt = (float2*)(ws + 67108864);      // 512*4097*8   = 16,781,312 B (end ~83.9 MB)

    kprep_kernel<<<512, KTPB, 0, stream>>>(log_dt, w_ri, Bri, Cri, Kt);
    transpose_in<<<dim3(8, 64, 8), TPB, 0, stream>>>(x, xt);
    conv_kernel<<<4096, CTPB, 0, stream>>>(xt, Kt, Dv, xt);  // y(+skip) overwrites xt rows
    transpose_out<<<dim3(8, 64, 8), TPB, 0, stream>>>(xt, out);
}

// Round 7
// 260.743 us; speedup vs baseline: 1.4649x; 1.0627x over previous
//
#include <hip/hip_runtime.h>
#include <math.h>

#define TPB 256
#define CTPB 512
#define KTPB 512

// ---------- complex helpers ----------
__device__ __forceinline__ float2 cmul(float2 a, float2 b) {
    return make_float2(a.x * b.x - a.y * b.y, a.x * b.y + a.y * b.x);
}
__device__ __forceinline__ float2 cdivf(float2 a, float2 b) {
    float inv = 1.0f / (b.x * b.x + b.y * b.y);
    return make_float2((a.x * b.x + a.y * b.y) * inv, (a.y * b.x - a.x * b.y) * inv);
}
__device__ __forceinline__ float2 cadd(float2 a, float2 b) { return make_float2(a.x + b.x, a.y + b.y); }
__device__ __forceinline__ float2 csub(float2 a, float2 b) { return make_float2(a.x - b.x, a.y - b.y); }
__device__ __forceinline__ float2 mul_i(float2 a, float d) {  // a * (i*d)
    return make_float2(-d * a.y, d * a.x);
}
__device__ __forceinline__ int brev11(int x) { return (int)(__brev((unsigned)x) >> 21); }
// base-8 digit reversal of a 12-bit index (4 digits)
__device__ __forceinline__ int rev8(int x) {
    return ((x & 7) << 9) | (((x >> 3) & 7) << 6) | (((x >> 6) & 7) << 3) | ((x >> 9) & 7);
}
// LDS bank swizzle. GF(2)-LINEAR: swz(a^b) == swz(a)^swz(b) -> per-tap offsets fold
// to compile-time XOR constants.
__device__ __forceinline__ int swz(int i) { return i ^ ((i >> 4) & 15) ^ ((i >> 8) & 15); }

// ---------- 8-point DFT cores ----------
__device__ __forceinline__ void dft8(const float2* x, float2* y, float d) {
    const float r = 0.70710678118f;
    float2 s0 = cadd(x[0], x[4]), t0 = csub(x[0], x[4]);
    float2 s1 = cadd(x[1], x[5]), t1 = csub(x[1], x[5]);
    float2 s2 = cadd(x[2], x[6]), t2 = csub(x[2], x[6]);
    float2 s3 = cadd(x[3], x[7]), t3 = csub(x[3], x[7]);
    t1 = cmul(t1, make_float2(r, d * r));
    t2 = mul_i(t2, d);
    t3 = cmul(t3, make_float2(-r, d * r));
    float2 u0 = cadd(s0, s2), v0 = csub(s0, s2);
    float2 u1 = cadd(s1, s3), v1 = mul_i(csub(s1, s3), d);
    y[0] = cadd(u0, u1); y[4] = csub(u0, u1);
    y[2] = cadd(v0, v1); y[6] = csub(v0, v1);
    float2 p0 = cadd(t0, t2), q0 = csub(t0, t2);
    float2 p1 = cadd(t1, t3), q1 = mul_i(csub(t1, t3), d);
    y[1] = cadd(p0, p1); y[5] = csub(p0, p1);
    y[3] = cadd(q0, q1); y[7] = csub(q0, q1);
}

// dft8 with x[4..7] == 0 (zero-padded upper half): level 1 vanishes (s_i = t_i = x_i)
__device__ __forceinline__ void dft8z(float2 x0, float2 x1, float2 x2, float2 x3,
                                      float2* y, float d) {
    const float r = 0.70710678118f;
    float2 u0 = cadd(x0, x2), v0 = csub(x0, x2);
    float2 u1 = cadd(x1, x3), v1 = mul_i(csub(x1, x3), d);
    float2 t1 = cmul(x1, make_float2(r, d * r));
    float2 t2 = mul_i(x2, d);
    float2 t3 = cmul(x3, make_float2(-r, d * r));
    float2 p0 = cadd(x0, t2), q0 = csub(x0, t2);
    float2 p1 = cadd(t1, t3), q1 = mul_i(csub(t1, t3), d);
    y[0] = cadd(u0, u1); y[4] = csub(u0, u1);
    y[2] = cadd(v0, v1); y[6] = csub(v0, v1);
    y[1] = cadd(p0, p1); y[5] = csub(p0, p1);
    y[3] = cadd(q0, q1); y[7] = csub(q0, q1);
}

// dft8 computing only outputs y[0..3] (the '+' halves) — for the discarded tail
__device__ __forceinline__ void dft8_lo(const float2* x, float2* y, float d) {
    const float r = 0.70710678118f;
    float2 s0 = cadd(x[0], x[4]), t0 = csub(x[0], x[4]);
    float2 s1 = cadd(x[1], x[5]), t1 = csub(x[1], x[5]);
    float2 s2 = cadd(x[2], x[6]), t2 = csub(x[2], x[6]);
    float2 s3 = cadd(x[3], x[7]), t3 = csub(x[3], x[7]);
    t1 = cmul(t1, make_float2(r, d * r));
    t2 = mul_i(t2, d);
    t3 = cmul(t3, make_float2(-r, d * r));
    float2 u0 = cadd(s0, s2), v0 = csub(s0, s2);
    float2 u1 = cadd(s1, s3), v1 = mul_i(csub(s1, s3), d);
    y[0] = cadd(u0, u1);
    y[2] = cadd(v0, v1);
    float2 p0 = cadd(t0, t2), q0 = csub(t0, t2);
    float2 p1 = cadd(t1, t3), q1 = mul_i(csub(t1, t3), d);
    y[1] = cadd(p0, p1);
    y[3] = cadd(q0, q1);
}

// ---------- single radix-8 stages for conv (1 butterfly/thread, N=4096, NT=512) ----------
template <int HB, int DIR>
__device__ __forceinline__ void dif_stage(float2* s, int tid) {
    __syncthreads();
    const int h = 1 << HB;
    int j = tid & (h - 1);
    int base = ((tid >> HB) << (HB + 3)) + j;
    int s0 = swz(base);
    float2 x[8];
#pragma unroll
    for (int k = 0; k < 8; ++k) x[k] = s[s0 ^ swz(k << HB)];
    float2 y[8];
    dft8(x, y, (float)DIR);
    if constexpr (HB != 0) {
        float ang = (float)DIR * 6.283185307179586f / (float)(h << 3) * (float)j;
        float c, sn;
        __sincosf(ang, &sn, &c);
        float2 w = make_float2(c, sn), wm = w;
        s[s0] = y[0];
#pragma unroll
        for (int m = 1; m < 8; ++m) {
            s[s0 ^ swz(m << HB)] = cmul(wm, y[m]);
            wm = cmul(wm, w);
        }
    } else {  // j == 0 -> w == 1: no twiddles
#pragma unroll
        for (int m = 0; m < 8; ++m) s[s0 ^ swz(m << HB)] = y[m];
    }
}

template <int HB, int DIR>
__device__ __forceinline__ void dit_stage(float2* s, int tid) {
    __syncthreads();
    const int h = 1 << HB;
    int j = tid & (h - 1);
    int base = ((tid >> HB) << (HB + 3)) + j;
    int s0 = swz(base);
    float2 x[8];
    if constexpr (HB != 0) {
        float ang = (float)DIR * 6.283185307179586f / (float)(h << 3) * (float)j;
        float c, sn;
        __sincosf(ang, &sn, &c);
        float2 w = make_float2(c, sn);
        x[0] = s[s0];
        float2 wm = w;
#pragma unroll
        for (int k = 1; k < 8; ++k) {
            x[k] = cmul(wm, s[s0 ^ swz(k << HB)]);
            wm = cmul(wm, w);
        }
    } else {  // j == 0 -> no twiddles
#pragma unroll
        for (int k = 0; k < 8; ++k) x[k] = s[s0 ^ swz(k << HB)];
    }
    float2 y[8];
    dft8(x, y, (float)DIR);
#pragma unroll
    for (int m = 0; m < 8; ++m) s[s0 ^ swz(m << HB)] = y[m];
}

// ---------- generic radix-8 DIF (for kprep), with h=1 twiddle skip ----------
template <int LOGN, int NT>
__device__ void fft8_dif(float2* s, int tid, float dir) {
    const int N = 1 << LOGN;
#pragma unroll
    for (int hb = LOGN - 3; hb >= 0; hb -= 3) {
        const int h = 1 << hb;
        const float astep = dir * 6.283185307179586f / (float)(h << 3);
        __syncthreads();
#pragma unroll
        for (int it = 0; it < (N >> 3) / NT; ++it) {
            const int b = tid + it * NT;
            int j = b & (h - 1);
            int base = ((b >> hb) << (hb + 3)) + j;
            int s0 = swz(base);
            float2 x[8];
#pragma unroll
            for (int k = 0; k < 8; ++k) x[k] = s[s0 ^ swz(k << hb)];
            float2 y[8];
            dft8(x, y, dir);
            if (hb != 0) {  // folds: hb is unroll-constant
                float ang = astep * (float)j;
                float c, sn;
                __sincosf(ang, &sn, &c);
                float2 w = make_float2(c, sn), wm = w;
                s[s0] = y[0];
#pragma unroll
                for (int m = 1; m < 8; ++m) {
                    s[s0 ^ swz(m << hb)] = cmul(wm, y[m]);
                    wm = cmul(wm, w);
                }
            } else {
#pragma unroll
                for (int m = 0; m < 8; ++m) s[s0 ^ swz(m << hb)] = y[m];
            }
        }
    }
    __syncthreads();
}

// ---------- radix-2 DIF (unswizzled), for the 2048-pt kernel inverse only ----------
template <int LOGN, int NT>
__device__ void fft_dif2(float2* s, int tid, float dir) {
    const int N = 1 << LOGN;
    for (int st = LOGN - 1; st >= 0; --st) {
        __syncthreads();
        int half = 1 << st;
        for (int b = tid; b < (N >> 1); b += NT) {
            int j  = b & (half - 1);
            int i0 = ((b >> st) << (st + 1)) + j;
            int i1 = i0 + half;
            float2 u = s[i0], v = s[i1];
            float2 d = make_float2(u.x - v.x, u.y - v.y);
            s[i0] = make_float2(u.x + v.x, u.y + v.y);
            if (half > 1) {
                float ang = dir * 3.14159265358979f * (float)j / (float)half;
                float c, sn;
                __sincosf(ang, &sn, &c);
                s[i1] = cmul(make_float2(c, sn), d);
            } else {
                s[i1] = d;
            }
        }
    }
    __syncthreads();
}

// ---------- prep (heterogeneous): blocks 0..511 = kf+kprep for channel hh;
// blocks 512..4607 = transpose_in tiles.  The two are independent (kprep: params->Kt;
// transpose: x->xt); fusing lets VALU-bound kprep blocks overlap BW-bound transpose
// blocks on the same CUs (time ~ max, not sum).  kf spectrum is overlaid on the upper
// half of s[] (written only after its last read; zero-pad scatter reclaims it). ----------
__global__ __launch_bounds__(KTPB) void prep_kernel(
    const float* __restrict__ log_dt, const float* __restrict__ w_ri,
    const float* __restrict__ Bri, const float* __restrict__ Cri,
    const float* __restrict__ x, float2* __restrict__ Kt, float* __restrict__ xt) {
    __shared__ float2 s[4096];
    __shared__ float2 kf_last;
    __shared__ float2 wds[32];
    __shared__ float aab[4][32], rab[4][32];
    __shared__ float qn[32], pn[32];
    const int tid = threadIdx.x;

    if (blockIdx.x >= 512) {
        // ---- transpose_in tile (512 threads, 2 iterations), tile buffer aliases s[]
        float* tile = (float*)s;                       // [64][65] floats = 16.6 KB
        const int tl_id = blockIdx.x - 512;            // 0..4095
        const int b  = tl_id >> 9;
        const int rem = tl_id & 511;
        const int t0 = (rem >> 3) << 6;                // 64 t-tiles
        const int h0 = (rem & 7) << 6;                 // 8 h-tiles
        const float4* xv = (const float4*)(x + ((size_t)b * 4096 + t0) * 512 + h0);
#pragma unroll
        for (int i = 0; i < 2; ++i) {
            int idx = tid + KTPB * i;                  // 0..1023
            int tl = idx >> 4, hq = idx & 15;
            float4 v = xv[(size_t)tl * 128 + hq];
            tile[tl * 65 + hq * 4 + 0] = v.x; tile[tl * 65 + hq * 4 + 1] = v.y;
            tile[tl * 65 + hq * 4 + 2] = v.z; tile[tl * 65 + hq * 4 + 3] = v.w;
        }
        __syncthreads();
        float* xo = xt + ((size_t)(b * 512 + h0)) * 4096 + t0;
#pragma unroll
        for (int i = 0; i < 2; ++i) {
            int idx = tid + KTPB * i;
            int hl = idx >> 4, tq = idx & 15;
            float4 v = make_float4(tile[(tq * 4 + 0) * 65 + hl], tile[(tq * 4 + 1) * 65 + hl],
                                   tile[(tq * 4 + 2) * 65 + hl], tile[(tq * 4 + 3) * 65 + hl]);
            ((float4*)(xo + (size_t)hl * 4096))[tq] = v;
        }
        return;
    }

    // ---- kf part (identical math; spectrum stored in kfs = s[2048..4096) + kf_last)
    const int hh = blockIdx.x;
    float2* kfs = s + 2048;
    const float dt = expf(log_dt[hh]);
    if (tid < 32) {
        float wr = w_ri[2 * tid] * dt, wi = w_ri[2 * tid + 1] * dt;
        wds[tid] = make_float2(wr, wi);
        qn[tid]  = wr * wr + wi * wi;
        pn[tid]  = -2.0f * wr;
    }
    __syncthreads();
    if (tid < 128) {
        int a = tid >> 6, b = (tid >> 5) & 1, n = tid & 31;
        const float* Cp = Cri + (((hh * 2 + a) * 32) + n) * 2;
        const float* Bp = Bri + (((hh * 2 + b) * 32) + n) * 2;
        float Cr = Cp[0], Ci = Cp[1], Br = Bp[0], Bi = Bp[1];
        float2 v = make_float2(Cr * Br + Ci * Bi, Cr * Bi - Ci * Br);  // conj(C)*B
        float2 wd = wds[n];
        aab[a * 2 + b][n] = -2.0f * (v.x * wd.x + v.y * wd.y);
        rab[a * 2 + b][n] = 2.0f * v.x;
    }
    __syncthreads();
    for (int f = tid; f < 2049; f += KTPB) {
        float th = (6.283185307179586f / 4096.0f) * (float)f;
        float cf = cosf(th), sf = sinf(th);
        float2 den = make_float2(1.0f + cf, -sf);      // 1 + freq
        float zt  = 2.0f * tanf(0.5f * th);
        float zt2 = zt * zt;
        float2 r00 = make_float2(0.f, 0.f), r01 = r00, r10 = r00, r11 = r00;
        for (int n = 0; n < 32; ++n) {
            float c   = qn[n] - zt2;
            float d   = pn[n] * zt;
            float inv = 1.0f / (c * c + d * d);
            float cc = c * inv, dd = d * inv;
            float a0 = aab[0][n], b0 = rab[0][n] * zt;
            r00.x += a0 * cc + b0 * dd; r00.y += b0 * cc - a0 * dd;
            float a1 = aab[1][n], b1 = rab[1][n] * zt;
            r01.x += a1 * cc + b1 * dd; r01.y += b1 * cc - a1 * dd;
            float a2 = aab[2][n], b2 = rab[2][n] * zt;
            r10.x += a2 * cc + b2 * dd; r10.y += b2 * cc - a2 * dd;
            float a3 = aab[3][n], b3 = rab[3][n] * zt;
            r11.x += a3 * cc + b3 * dd; r11.y += b3 * cc - a3 * dd;
        }
        r00.x *= dt; r00.y *= dt; r01.x *= dt; r01.y *= dt;
        r10.x *= dt; r10.y *= dt; r11.x *= dt; r11.y *= dt;
        float2 q  = cdivf(cmul(r01, r10), make_float2(1.0f + r11.x, r11.y));
        float2 k0 = make_float2(r00.x - q.x, r00.y - q.y);
        float2 kv = cmul(k0, cdivf(make_float2(2.0f, 0.0f), den));
        if (f < 2048) kfs[f] = kv; else kf_last = kv;
    }
    __syncthreads();

    // ---- kprep part: reads spectrum from s[2048..] / kf_last, writes s[0..2048)
    for (int m = tid; m < 2048; m += KTPB) {
        float2 Xm = kfs[m];
        float2 Xc = (m == 0) ? kf_last : kfs[2048 - m];
        if (m == 0) { Xm.y = 0.0f; Xc.y = 0.0f; }
        float2 A  = make_float2(Xm.x + Xc.x, Xm.y - Xc.y);
        float2 Bv = make_float2(Xm.x - Xc.x, Xm.y + Xc.y);
        float ang = (3.14159265358979f / 2048.0f) * (float)m;
        float c, sn;
        __sincosf(ang, &sn, &c);
        float2 O = cmul(make_float2(c, sn), Bv);
        s[m] = make_float2(0.5f * (A.x - O.y), 0.5f * (A.y + O.x));
    }
    fft_dif2<11, KTPB>(s, tid, +1.0f);  // inverse, natural-in -> bitrev-out (unswizzled)
    float2 reg[4];
    const float sc = 1.0f / 2048.0f;
#pragma unroll
    for (int i = 0; i < 4; ++i) {
        int t = tid + KTPB * i;  // 0..2047
        float2 v = s[brev11(t)];
        reg[i] = make_float2(v.x * sc, v.y * sc);
    }
    __syncthreads();
#pragma unroll
    for (int i = 0; i < 4; ++i) {
        int t = tid + KTPB * i;
        s[swz(t)]        = reg[i];
        s[swz(t + 2048)] = make_float2(0.f, 0.f);   // reclaims the dead kfs region
    }
    fft8_dif<12, KTPB>(s, tid, -1.0f);  // slot p holds Y[rev8(p)]
    float2* K = Kt + (size_t)hh * 4097;
    for (int p = tid; p < 4096; p += KTPB) {
        int j  = rev8(p);
        int jc = (4096 - j) & 4095;
        int pc = rev8(jc);
        float2 Yj = s[swz(p)], Yc = s[swz(pc)];
        float2 A  = make_float2(Yj.x + Yc.x, Yj.y - Yc.y);
        float2 Bv = make_float2(Yj.x - Yc.x, Yj.y + Yc.y);
        float ang = -(3.14159265358979f / 4096.0f) * (float)j;
        float c, sn;
        __sincosf(ang, &sn, &c);
        float2 t2 = cmul(make_float2(c, sn), make_float2(Bv.y, -Bv.x));
        K[p] = make_float2(0.5f * (A.x + t2.x), 0.5f * (A.y + t2.y));
        if (p == 0) K[4096] = make_float2(Yj.x - Yj.y, 0.0f);
    }
}

// ---------- fused conv: y = irfft8192(rfft8192(x)*K~)[0:4096]*1 + D*x, radix-8, reg end-stages ----------
__global__ __launch_bounds__(CTPB) void conv_kernel(const float* xt,
                                                    const float2* __restrict__ Kt,
                                                    const float* __restrict__ Dv,
                                                    float* yt) {
    __shared__ float2 s[4096];
    const int row = blockIdx.x, tid = threadIdx.x;
    const int hch = row & 511;
    const int stid = swz(tid);
    const float2* xr = (const float2*)(xt + (size_t)row * 4096);

    // ---- D1 (DIF h=512) in registers; upper half is the zero pad -> dft8z
    {
        float2 x0 = xr[tid], x1 = xr[tid + 512], x2 = xr[tid + 1024], x3 = xr[tid + 1536];
        float2 y[8];
        dft8z(x0, x1, x2, x3, y, -1.0f);
        float ang = -(6.283185307179586f / 4096.0f) * (float)tid;
        float c, sn;
        __sincosf(ang, &sn, &c);
        float2 w = make_float2(c, sn), wm = w;
        s[stid] = y[0];
#pragma unroll
        for (int m = 1; m < 8; ++m) {
            s[stid ^ swz(m << 9)] = cmul(wm, y[m]);
            wm = cmul(wm, w);
        }
    }
    dif_stage<6, -1>(s, tid);
    dif_stage<3, -1>(s, tid);
    dif_stage<0, -1>(s, tid);
    __syncthreads();
    // ---- pointwise multiply in digit-reversed Hermitian-packed domain
    const float2* K = Kt + (size_t)hch * 4097;
#pragma unroll
    for (int i = 0; i < 8; ++i) {
        int p  = tid + CTPB * i;
        int sp = stid ^ swz(CTPB * i);
        if (p == 0) {  // j=0 pairs with bin 4096
            float2 Y0 = s[sp];
            float X0 = Y0.x + Y0.y;
            float Xn = Y0.x - Y0.y;
            float Z0 = X0 * K[0].x;
            float Zn = Xn * K[4096].x;
            s[sp] = make_float2(0.5f * (Z0 + Zn), 0.5f * (Z0 - Zn));
            continue;
        }
        int j  = rev8(p);
        int jc = 4096 - j;
        int pc = rev8(jc & 4095);
        if (pc < p) continue;  // pair owner has the smaller slot
        float2 Yj = s[sp], Yc = s[swz(pc)];
        float2 A  = make_float2(Yj.x + Yc.x, Yj.y - Yc.y);
        float2 Bv = make_float2(Yj.x - Yc.x, Yj.y + Yc.y);
        float ang = -(3.14159265358979f / 4096.0f) * (float)j;
        float c, sn;
        __sincosf(ang, &sn, &c);
        float2 W = make_float2(c, sn);
        float2 t2 = cmul(W, make_float2(Bv.y, -Bv.x));
        float2 Xj = make_float2(0.5f * (A.x + t2.x), 0.5f * (A.y + t2.y));
        float2 t2c = cmul(make_float2(-W.x, W.y), make_float2(Bv.y, Bv.x));
        float2 Xc2 = make_float2(0.5f * (A.x + t2c.x), 0.5f * (-A.y + t2c.y));
        float2 Zj = cmul(Xj, K[p]);
        float2 Zc = cmul(Xc2, K[pc]);
        float2 A2 = make_float2(Zj.x + Zc.x, Zj.y - Zc.y);
        float2 B2 = make_float2(Zj.x - Zc.x, Zj.y + Zc.y);
        float2 O2 = cmul(make_float2(W.x, -W.y), B2);
        s[sp] = make_float2(0.5f * (A2.x - O2.y), 0.5f * (A2.y + O2.x));
        if (pc != p) {
            float2 O2c = cmul(make_float2(-W.x, -W.y), make_float2(-B2.x, B2.y));
            s[swz(pc)] = make_float2(0.5f * (A2.x - O2c.y), 0.5f * (-A2.y + O2c.x));
        }
    }
    dit_stage<0, 1>(s, tid);
    dit_stage<3, 1>(s, tid);
    dit_stage<6, 1>(s, tid);
    __syncthreads();
    // ---- I4 (DIT h=512) in registers; keep only first 4096 samples; fuse D*x skip
    {
        float ang = (6.283185307179586f / 4096.0f) * (float)tid;
        float c, sn;
        __sincosf(ang, &sn, &c);
        float2 w = make_float2(c, sn);
        float2 x[8];
        x[0] = s[stid];
        float2 wm = w;
#pragma unroll
        for (int k = 1; k < 8; ++k) {
            x[k] = cmul(wm, s[stid ^ swz(k << 9)]);
            wm = cmul(wm, w);
        }
        float2 y[4];
        dft8_lo(x, y, 1.0f);
        const float D = Dv[hch];
        float2* yo = (float2*)(yt + (size_t)row * 4096);
        const float sc = 1.0f / 4096.0f;
#pragma unroll
        for (int m = 0; m < 4; ++m) {
            int t2 = tid + (m << 9);
            float2 xin = xr[t2];  // re-read own row (L2-warm); xt/yt alias is per-element safe
            yo[t2] = make_float2(y[m].x * sc + D * xin.x, y[m].y * sc + D * xin.y);
        }
    }
}

// ---------- transpose out (pure): out[b,t,h] = yt[(b*512+h),t] ----------
__global__ __launch_bounds__(TPB) void transpose_out(const float* __restrict__ yt,
                                                     float* __restrict__ out) {
    __shared__ float tile[64][65];
    const int b = blockIdx.z, t0 = blockIdx.y * 64, h0 = blockIdx.x * 64;
    const int tid = threadIdx.x;
    const float* yp = yt + ((size_t)(b * 512 + h0)) * 4096 + t0;
#pragma unroll
    for (int i = 0; i < 4; ++i) {
        int idx = tid + TPB * i;
        int hl = idx >> 4, tq = idx & 15;
        float4 v = ((const float4*)(yp + (size_t)hl * 4096))[tq];
        tile[tq * 4 + 0][hl] = v.x; tile[tq * 4 + 1][hl] = v.y;
        tile[tq * 4 + 2][hl] = v.z; tile[tq * 4 + 3][hl] = v.w;
    }
    __syncthreads();
    float4* ov = (float4*)(out + ((size_t)b * 4096 + t0) * 512 + h0);
#pragma unroll
    for (int i = 0; i < 4; ++i) {
        int idx = tid + TPB * i;
        int tl = idx >> 4, hq = idx & 15;
        float4 v = make_float4(tile[tl][4 * hq + 0], tile[tl][4 * hq + 1],
                               tile[tl][4 * hq + 2], tile[tl][4 * hq + 3]);
        ov[(size_t)tl * 128 + hq] = v;
    }
}

extern "C" void kernel_launch(void* const* d_in, const int* in_sizes, int n_in,
                              void* d_out, int out_size, void* d_ws, size_t ws_size,
                              hipStream_t stream) {
    (void)in_sizes; (void)n_in; (void)out_size; (void)ws_size;
    const float* x      = (const float*)d_in[0];  // [8,4096,512]
    const float* log_dt = (const float*)d_in[1];  // [512]
    const float* w_ri   = (const float*)d_in[2];  // [32,2]
    const float* Bri    = (const float*)d_in[3];  // [512,2,32,2]
    const float* Cri    = (const float*)d_in[4];  // [512,2,32,2]
    const float* Dv     = (const float*)d_in[5];  // [512]
    float* out = (float*)d_out;

    char* ws = (char*)d_ws;
    float*  xt = (float*)(ws);                  // 8*512*4096*4 = 67,108,864 B (reused as yt)
    float2* Kt = (float2*)(ws + 67108864);      // 512*4097*8   = 16,781,312 B (end ~83.9 MB)

    prep_kernel<<<512 + 4096, KTPB, 0, stream>>>(log_dt, w_ri, Bri, Cri, x, Kt, xt);
    conv_kernel<<<4096, CTPB, 0, stream>>>(xt, Kt, Dv, xt);  // y(+skip) overwrites xt rows
    transpose_out<<<dim3(8, 64, 8), TPB, 0, stream>>>(xt, out);
}